// Round 13
// baseline (631.402 us; speedup 1.0000x reference)
//
#include <hip/hip_runtime.h>
#include <hip/hip_bf16.h>
#include <cstdint>
#include <cstddef>

#define KEYSHIFT 20
#define COLMASK 0xFFFFFu
#define EPB 8192    // edges per count/scatter block (1024 threads x 8)
#define SUB 4096    // staged sub-chunk inside scatter (fits 54KB LDS)
#define BSHIFT 8    // 256 rows per bucket
#define NRB 256     // rows per bucket (1 << BSHIFT)
#define CCAP 3072   // LDS sort capacity per bucket (avg ~2560, max ~2750)

typedef short bf16x8 __attribute__((ext_vector_type(8)));
typedef float f32x4 __attribute__((ext_vector_type(4)));

// bf16 pack/unpack: RNE; accumulation fp32.
__device__ __forceinline__ unsigned short f2bf(float f) {
    uint32_t u = __float_as_uint(f);
    u += ((u >> 16) & 1u) + 0x7fffu;   // RNE
    return (unsigned short)(u >> 16);
}
__device__ __forceinline__ float bf2f(unsigned short h) {
    return __uint_as_float(((uint32_t)h) << 16);
}

// ---------------------------------------------------------------------------
// Host-side reproduction of np.random.RandomState(2).permutation(64).
// ---------------------------------------------------------------------------
static uint64_t compute_mask_bits() {
    uint32_t mt[624];
    mt[0] = 2u;
    for (int i = 1; i < 624; i++)
        mt[i] = 1812433253u * (mt[i - 1] ^ (mt[i - 1] >> 30)) + (uint32_t)i;
    int mti = 624;
    auto genrand = [&]() -> uint32_t {
        if (mti >= 624) {
            for (int k = 0; k < 624; k++) {
                uint32_t y = (mt[k] & 0x80000000u) | (mt[(k + 1) % 624] & 0x7fffffffu);
                mt[k] = mt[(k + 397) % 624] ^ (y >> 1) ^ ((y & 1u) ? 2567483615u : 0u);
            }
            mti = 0;
        }
        uint32_t y = mt[mti++];
        y ^= y >> 11;
        y ^= (y << 7) & 2636928640u;
        y ^= (y << 15) & 4022730752u;
        y ^= y >> 18;
        return y;
    };
    int arr[64];
    for (int i = 0; i < 64; i++) arr[i] = i;
    for (int i = 63; i >= 1; i--) {
        uint32_t mask = (uint32_t)i;
        mask |= mask >> 1; mask |= mask >> 2; mask |= mask >> 4;
        mask |= mask >> 8; mask |= mask >> 16;
        uint32_t v;
        do { v = genrand() & mask; } while (v > (uint32_t)i);
        int tmp = arr[i]; arr[i] = arr[v]; arr[v] = tmp;
    }
    uint64_t bits = 0;
    for (int d = 0; d < 64; d++)
        if (arr[d] >= 38) bits |= (1ull << d);
    return bits;
}

// ---------------------------------------------------------------------------
__global__ void flag_kernel(const int* __restrict__ users, const int* __restrict__ items,
                            unsigned char* __restrict__ flag, int B, int U) {
    int i = blockIdx.x * 256 + threadIdx.x;
    if (i < B) flag[users[i]] = 1;
    else if (i < 2 * B) flag[U + items[i - B]] = 1;
}

__global__ void flist_kernel(const unsigned char* __restrict__ flag,
                             int* __restrict__ flist, int* __restrict__ fcount, int n) {
    int i = blockIdx.x * 256 + threadIdx.x;
    if (i < n && flag[i]) {
        int p = atomicAdd(fcount, 1);
        flist[p] = i;
    }
}

// ---------------------------------------------------------------------------
__global__ void c1_kernel(const float* __restrict__ rating_emb, const float* __restrict__ W1,
                          const float* __restrict__ b1, float* __restrict__ c1_all) {
    int r = blockIdx.x;
    int t = threadIdx.x;  // 64 threads
    const float* W1r = W1 + (size_t)r * (128 * 64);
    float acc = b1[r * 64 + t];
    for (int k = 0; k < 64; k++)
        acc += rating_emb[r * 64 + k] * W1r[(64 + k) * 64 + t];
    c1_all[r * 64 + t] = acc;
}

// ---------------------------------------------------------------------------
// Split-bf16 W fragment pack for MFMA mlp (R22, proven).
// ---------------------------------------------------------------------------
__global__ void packw_kernel(const float* __restrict__ W1, const float* __restrict__ W2,
                             short* __restrict__ wpack) {
    int r = blockIdx.x;
    int t = threadIdx.x;  // 256
    const float* W1r = W1 + (size_t)r * (128 * 64);
    const float* W2r = W2 + (size_t)r * (64 * 64);
    for (int e = t; e < 2 * 4 * 2 * 64 * 8; e += 256) {
        int i = e & 7;
        int lane = (e >> 3) & 63;
        int kc = (e >> 9) & 1;
        int ct = (e >> 10) & 3;
        int g = (e >> 12) & 1;
        int k = kc * 32 + ((lane >> 4) << 3) + i;
        int col = (ct << 4) + (lane & 15);
        float w = (g == 0) ? W1r[k * 64 + col] : W2r[k * 64 + col];
        unsigned short hi = f2bf(w);
        unsigned short lo = f2bf(w - bf2f(hi));
        size_t fb = ((((size_t)r * 2 + g) * 4 + ct) * 2 + kc) * 2;
        wpack[(fb + 0) * 512 + lane * 8 + i] = (short)hi;
        wpack[(fb + 1) * 512 + lane * 8 + i] = (short)lo;
    }
}

// ---------------------------------------------------------------------------
// Build pass A (batched): LDS histogram + one reserve-atomic per bucket.
// R24: 4-wide edge-read batching (count was 0.5 TB/s latency-bound).
// ---------------------------------------------------------------------------
__global__ __launch_bounds__(1024) void bucket_count_kernel(
    const int* __restrict__ rows, int* __restrict__ gcnt,
    int* __restrict__ blockBase, int E, int K, int nb) {
    __shared__ int hist[2048];
    int r = blockIdx.y, blk = blockIdx.x, t = threadIdx.x;
    for (int i = t; i < K; i += 1024) hist[i] = 0;
    __syncthreads();
    size_t base = (size_t)r * E + (size_t)blk * EPB;
    int cnt = E - blk * EPB;
    if (cnt > EPB) cnt = EPB;
    for (int k = t; k < cnt; k += 4096) {
        int i1 = k + 1024, i2 = k + 2048, i3 = k + 3072;
        int r0 = rows[base + k];
        int r1 = rows[base + (i1 < cnt ? i1 : k)];
        int r2 = rows[base + (i2 < cnt ? i2 : k)];
        int r3 = rows[base + (i3 < cnt ? i3 : k)];
        atomicAdd(&hist[r0 >> BSHIFT], 1);
        if (i1 < cnt) atomicAdd(&hist[r1 >> BSHIFT], 1);
        if (i2 < cnt) atomicAdd(&hist[r2 >> BSHIFT], 1);
        if (i3 < cnt) atomicAdd(&hist[r3 >> BSHIFT], 1);
    }
    __syncthreads();
    for (int i = t; i < K; i += 1024) {
        int c = hist[i];
        int bb = (c > 0) ? atomicAdd(&gcnt[r * K + i], c) : 0;
        blockBase[((size_t)r * nb + blk) * K + i] = bb;
    }
}

// ---------------------------------------------------------------------------
__global__ void bucket_scan_kernel(const int* __restrict__ gcnt,
                                   int* __restrict__ bptr, int K) {
    __shared__ int sh[256];
    int r = blockIdx.x;
    int t = threadIdx.x;
    int base = t * 8;
    int v[8];
    int s = 0;
    #pragma unroll
    for (int j = 0; j < 8; j++) {
        int idx = base + j;
        v[j] = (idx < K) ? gcnt[r * K + idx] : 0;
        s += v[j];
    }
    sh[t] = s;
    __syncthreads();
    for (int off = 1; off < 256; off <<= 1) {
        int x = (t >= off) ? sh[t - off] : 0;
        __syncthreads();
        sh[t] += x;
        __syncthreads();
    }
    int run = sh[t] - s;
    #pragma unroll
    for (int j = 0; j < 8; j++) {
        int idx = base + j;
        if (idx <= K) bptr[r * (K + 1) + idx] = run;
        run += v[j];
    }
}

// ---------------------------------------------------------------------------
// Build pass B: LDS-STAGED scatter (K <= 512).
// ---------------------------------------------------------------------------
__global__ __launch_bounds__(1024) void bucket_scatter_kernel(
    const int* __restrict__ rows, const int* __restrict__ cols,
    const float* __restrict__ vals, const int* __restrict__ bptr,
    const int* __restrict__ blockBase, uint2* __restrict__ rec,
    int E, int K, long long eStride, long long pStride,
    long long bbStride, long long rStride) {
    __shared__ uint2 staged[SUB];   // 32KB
    __shared__ int gaddr[SUB];      // 16KB
    __shared__ int cursor[512];
    __shared__ int lhist[512];
    __shared__ int aux[512];
    int r = blockIdx.y;
    const int* rows_r = rows + (size_t)r * eStride;
    const int* cols_r = cols + (size_t)r * eStride;
    const float* vals_r = vals + (size_t)r * eStride;
    const int* bptr_r = bptr + (size_t)r * pStride;
    const int* bb_r = blockBase + (size_t)r * bbStride;
    uint2* rec_r = rec + (size_t)r * rStride;
    int blk = blockIdx.x, t = threadIdx.x;
    if (t < 512)
        cursor[t] = (t < K) ? (bptr_r[t] + bb_r[(size_t)blk * K + t]) : 0;
    size_t base = (size_t)blk * EPB;
    int cnt = E - blk * EPB;
    if (cnt > EPB) cnt = EPB;
    for (int c0 = 0; c0 < cnt; c0 += SUB) {
        int scnt = cnt - c0;
        if (scnt > SUB) scnt = SUB;
        if (t < 512) lhist[t] = 0;
        __syncthreads();
        int bkt_[4], lpos_[4];
        uint2 rv_[4];
        #pragma unroll
        for (int q = 0; q < 4; q++) {
            int kk = (q << 10) + t;
            bkt_[q] = -1;
            if (kk < scnt) {
                size_t g = base + c0 + kk;
                int row = rows_r[g];
                int b = row >> BSHIFT;
                bkt_[q] = b;
                rv_[q] = make_uint2(((uint32_t)(row & (NRB - 1)) << KEYSHIFT) |
                                        (uint32_t)cols_r[g],
                                    __float_as_uint(vals_r[g]));
                lpos_[q] = atomicAdd(&lhist[b], 1);
            }
        }
        __syncthreads();
        int v = (t < 512) ? lhist[t] : 0;
        if (t < 512) aux[t] = v;
        __syncthreads();
        for (int off = 1; off < 512; off <<= 1) {
            int x = 0;
            if (t >= off && t < 512) x = aux[t - off];
            __syncthreads();
            if (t < 512) aux[t] += x;
            __syncthreads();
        }
        if (t < 512) {
            int ex = aux[t] - v;
            int gb = cursor[t];
            cursor[t] = gb + v;
            lhist[t] = ex;
            aux[t] = gb - ex;
        }
        __syncthreads();
        #pragma unroll
        for (int q = 0; q < 4; q++) {
            if (bkt_[q] >= 0) {
                int sidx = lhist[bkt_[q]] + lpos_[q];
                staged[sidx] = rv_[q];
                gaddr[sidx] = aux[bkt_[q]] + sidx;
            }
        }
        __syncthreads();
        for (int i = t; i < scnt; i += 1024)
            rec_r[gaddr[i]] = staged[i];
        __syncthreads();
    }
}

// ---------------------------------------------------------------------------
// Build pass B legacy (direct scatter) — only used if K > 512.
// ---------------------------------------------------------------------------
__global__ __launch_bounds__(1024) void bucket_scatter_legacy(
    const int* __restrict__ rows, const int* __restrict__ cols,
    const float* __restrict__ vals, const int* __restrict__ bptr,
    const int* __restrict__ blockBase, uint2* __restrict__ rec,
    int E, int K, long long eStride, long long pStride,
    long long bbStride, long long rStride) {
    __shared__ int cursor[2048];
    int r = blockIdx.y;
    const int* rows_r = rows + (size_t)r * eStride;
    const int* cols_r = cols + (size_t)r * eStride;
    const float* vals_r = vals + (size_t)r * eStride;
    const int* bptr_r = bptr + (size_t)r * pStride;
    const int* bb_r = blockBase + (size_t)r * bbStride;
    uint2* rec_r = rec + (size_t)r * rStride;
    int blk = blockIdx.x, t = threadIdx.x;
    for (int i = t; i < K; i += 1024)
        cursor[i] = bptr_r[i] + bb_r[(size_t)blk * K + i];
    __syncthreads();
    size_t base = (size_t)blk * EPB;
    int cnt = E - blk * EPB;
    if (cnt > EPB) cnt = EPB;
    for (int k = t; k < cnt; k += 1024) {
        int row = rows_r[base + k];
        int b = row >> BSHIFT;
        int pos = atomicAdd(&cursor[b], 1);
        uint32_t key = ((uint32_t)(row & (NRB - 1)) << KEYSHIFT) | (uint32_t)cols_r[base + k];
        rec_r[pos] = make_uint2(key, __float_as_uint(vals_r[base + k]));
    }
}

// ---------------------------------------------------------------------------
// Build pass C: per-bucket counting sort, fully in LDS; emits row_ptr.
// ---------------------------------------------------------------------------
__global__ __launch_bounds__(256) void bucket_sort_kernel(
    const uint2* __restrict__ rec, uint2* __restrict__ srec,
    const int* __restrict__ bptr, int* __restrict__ rp, int K, int N,
    long long rStride, long long pStride, long long rpStride) {
    __shared__ uint2 staged[CCAP];  // 24KB
    __shared__ int hist[NRB];
    __shared__ int excl[NRB];
    int r = blockIdx.y;
    const uint2* rec_r = rec + (size_t)r * rStride;
    uint2* srec_r = srec + (size_t)r * rStride;
    const int* bptr_r = bptr + (size_t)r * pStride;
    int* rp_r = rp + (size_t)r * rpStride;
    int b = blockIdx.x;
    int t = threadIdx.x;          // 256 threads == NRB
    hist[t] = 0;
    __syncthreads();
    int start = bptr_r[b], end = bptr_r[b + 1];
    int m = end - start;
    for (int e = start + t; e < end; e += 256)
        atomicAdd(&hist[rec_r[e].x >> KEYSHIFT], 1);
    __syncthreads();
    int v = hist[t];
    excl[t] = v;
    __syncthreads();
    for (int off = 1; off < 256; off <<= 1) {
        int x = (t >= off) ? excl[t - off] : 0;
        __syncthreads();
        excl[t] += x;
        __syncthreads();
    }
    int ex = excl[t] - v;
    excl[t] = ex;
    hist[t] = 0;
    int row = b * NRB + t;
    if (row < N) rp_r[row] = start + ex;
    if (b == K - 1 && t == 0) rp_r[N] = bptr_r[K];
    __syncthreads();
    if (m <= CCAP) {
        for (int e = start + t; e < end; e += 256) {
            uint2 rr = rec_r[e];
            int rel = (int)(rr.x >> KEYSHIFT);
            int pos = excl[rel] + atomicAdd(&hist[rel], 1);
            staged[pos] = rr;
        }
        __syncthreads();
        for (int i = t; i < m; i += 256)
            srec_r[start + i] = staged[i];
    } else {
        for (int e = start + t; e < end; e += 256) {
            uint2 rr = rec_r[e];
            int rel = (int)(rr.x >> KEYSHIFT);
            int pos = start + excl[rel] + atomicAdd(&hist[rel], 1);
            srec_r[pos] = rr;
        }
    }
}

// ---------------------------------------------------------------------------
// MFMA MLP v2 (R24): ratings processed in PAIRS for ILP. R12's 75us had
// MfmaUtil 12 / VALU 23 / Occ 31 — a serial B-load->MFMA->T-repack chain
// with nothing to overlap. GEMM1 of rating rr+1 depends only on X (regs),
// so interleaving two ratings doubles ILP at every stall point: two accs,
// two B-frag streams, two wave-private sT buffers, paired repack/GEMM2.
// Split-bf16 3-term precision (proven R22). Tail rating handled single.
// ---------------------------------------------------------------------------
__global__ __launch_bounds__(256) void mlp_kernel(
    const float* __restrict__ user_emb, const float* __restrict__ item_emb,
    const short* __restrict__ wpack, const float* __restrict__ c1_all,
    const float* __restrict__ b2,
    unsigned short* __restrict__ prev, long long prevStride,
    float* __restrict__ out_acc, const unsigned char* __restrict__ flag,
    int r0, int nr, int n_rows, int U, int init) {
    __shared__ float sTa[64 * 68];   // hidden layer, rating a (17.4KB)
    __shared__ float sTb[64 * 68];   // hidden layer, rating b (17.4KB)

    int t = threadIdx.x;
    int wv = t >> 6;
    int l = t & 63;
    int row0 = blockIdx.x * 64;
    int arow = row0 + (wv << 4) + (l & 15);      // A-operand row
    int kb = (l >> 4) << 3;                       // k base within 32-chunk
    int trow = (wv << 4) + (l & 15);              // local T row for A-frags

    bf16x8 xh0, xh1, xl0, xl1;
    {
        float xv[16];
        #pragma unroll
        for (int i = 0; i < 16; i++) xv[i] = 0.f;
        if (arow < n_rows) {
            const float* src = (arow < U) ? (user_emb + (size_t)arow * 64)
                                          : (item_emb + (size_t)(arow - U) * 64);
            float4 p0 = *(const float4*)(src + kb);
            float4 p1 = *(const float4*)(src + kb + 4);
            float4 p2 = *(const float4*)(src + 32 + kb);
            float4 p3 = *(const float4*)(src + 32 + kb + 4);
            xv[0] = p0.x; xv[1] = p0.y; xv[2] = p0.z; xv[3] = p0.w;
            xv[4] = p1.x; xv[5] = p1.y; xv[6] = p1.z; xv[7] = p1.w;
            xv[8] = p2.x; xv[9] = p2.y; xv[10] = p2.z; xv[11] = p2.w;
            xv[12] = p3.x; xv[13] = p3.y; xv[14] = p3.z; xv[15] = p3.w;
        }
        #pragma unroll
        for (int i = 0; i < 8; i++) {
            unsigned short hi = f2bf(xv[i]);
            xh0[i] = (short)hi;
            xl0[i] = (short)f2bf(xv[i] - bf2f(hi));
        }
        #pragma unroll
        for (int i = 0; i < 8; i++) {
            unsigned short hi = f2bf(xv[8 + i]);
            xh1[i] = (short)hi;
            xl1[i] = (short)f2bf(xv[8 + i] - bf2f(hi));
        }
    }

    int dr0 = row0 + (wv << 4) + ((l >> 4) << 2);  // D rows dr0..dr0+3
    bool va0 = (dr0 + 0) < n_rows, va1 = (dr0 + 1) < n_rows;
    bool va2 = (dr0 + 2) < n_rows, va3 = (dr0 + 3) < n_rows;
    bool fl0 = va0 && flag[dr0 + 0], fl1 = va1 && flag[dr0 + 1];
    bool fl2 = va2 && flag[dr0 + 2], fl3 = va3 && flag[dr0 + 3];
    float oa[16];
    #pragma unroll
    for (int i = 0; i < 16; i++) oa[i] = 0.f;

    for (int rr = r0; rr < r0 + nr; rr += 2) {
        int rr2 = rr + 1;
        bool has2 = (rr2 < r0 + nr);
        const short* wp1a = wpack + ((size_t)rr * 2 + 0) * 16 * 512;
        const short* wp2a = wpack + ((size_t)rr * 2 + 1) * 16 * 512;
        const short* wp1b = wpack + ((size_t)(has2 ? rr2 : rr) * 2 + 0) * 16 * 512;
        const short* wp2b = wpack + ((size_t)(has2 ? rr2 : rr) * 2 + 1) * 16 * 512;

        // GEMM1 for both ratings, interleaved per col-tile.
        #pragma unroll
        for (int ct = 0; ct < 4; ct++) {
            float c1a = c1_all[rr * 64 + (ct << 4) + (l & 15)];
            f32x4 acca = {c1a, c1a, c1a, c1a};
            f32x4 accb = {0.f, 0.f, 0.f, 0.f};
            if (has2) {
                float c1b = c1_all[rr2 * 64 + (ct << 4) + (l & 15)];
                accb = (f32x4){c1b, c1b, c1b, c1b};
            }
            #pragma unroll
            for (int kc = 0; kc < 2; kc++) {
                const short* fba = wp1a + ((ct * 2 + kc) * 2) * 512 + l * 8;
                const short* fbb = wp1b + ((ct * 2 + kc) * 2) * 512 + l * 8;
                bf16x8 bha = *(const bf16x8*)(fba);
                bf16x8 bla = *(const bf16x8*)(fba + 512);
                bf16x8 bhb = *(const bf16x8*)(fbb);
                bf16x8 blb = *(const bf16x8*)(fbb + 512);
                bf16x8 ah = (kc == 0) ? xh0 : xh1;
                bf16x8 al = (kc == 0) ? xl0 : xl1;
                acca = __builtin_amdgcn_mfma_f32_16x16x32_bf16(ah, bha, acca, 0, 0, 0);
                accb = __builtin_amdgcn_mfma_f32_16x16x32_bf16(ah, bhb, accb, 0, 0, 0);
                acca = __builtin_amdgcn_mfma_f32_16x16x32_bf16(al, bha, acca, 0, 0, 0);
                accb = __builtin_amdgcn_mfma_f32_16x16x32_bf16(al, bhb, accb, 0, 0, 0);
                acca = __builtin_amdgcn_mfma_f32_16x16x32_bf16(ah, bla, acca, 0, 0, 0);
                accb = __builtin_amdgcn_mfma_f32_16x16x32_bf16(ah, blb, accb, 0, 0, 0);
            }
            #pragma unroll
            for (int i = 0; i < 4; i++) {
                int sr = (wv << 4) + ((l >> 4) << 2) + i;
                float va = acca[i];
                va = (va >= 0.f) ? va : 0.01f * va;
                sTa[sr * 68 + (ct << 4) + (l & 15)] = va;
                if (has2) {
                    float vb = accb[i];
                    vb = (vb >= 0.f) ? vb : 0.01f * vb;
                    sTb[sr * 68 + (ct << 4) + (l & 15)] = vb;
                }
            }
        }
        // T A-fragments for both ratings (wave-private rows, no barrier).
        bf16x8 tha0, tha1, tla0, tla1, thb0, thb1, tlb0, tlb1;
        {
            float4 t0 = *(const float4*)(sTa + trow * 68 + kb);
            float4 t1 = *(const float4*)(sTa + trow * 68 + kb + 4);
            float4 t2 = *(const float4*)(sTa + trow * 68 + 32 + kb);
            float4 t3 = *(const float4*)(sTa + trow * 68 + 32 + kb + 4);
            float tv[16] = {t0.x, t0.y, t0.z, t0.w, t1.x, t1.y, t1.z, t1.w,
                            t2.x, t2.y, t2.z, t2.w, t3.x, t3.y, t3.z, t3.w};
            #pragma unroll
            for (int i = 0; i < 8; i++) {
                unsigned short hi = f2bf(tv[i]);
                tha0[i] = (short)hi;
                tla0[i] = (short)f2bf(tv[i] - bf2f(hi));
            }
            #pragma unroll
            for (int i = 0; i < 8; i++) {
                unsigned short hi = f2bf(tv[8 + i]);
                tha1[i] = (short)hi;
                tla1[i] = (short)f2bf(tv[8 + i] - bf2f(hi));
            }
        }
        if (has2) {
            float4 t0 = *(const float4*)(sTb + trow * 68 + kb);
            float4 t1 = *(const float4*)(sTb + trow * 68 + kb + 4);
            float4 t2 = *(const float4*)(sTb + trow * 68 + 32 + kb);
            float4 t3 = *(const float4*)(sTb + trow * 68 + 32 + kb + 4);
            float tv[16] = {t0.x, t0.y, t0.z, t0.w, t1.x, t1.y, t1.z, t1.w,
                            t2.x, t2.y, t2.z, t2.w, t3.x, t3.y, t3.z, t3.w};
            #pragma unroll
            for (int i = 0; i < 8; i++) {
                unsigned short hi = f2bf(tv[i]);
                thb0[i] = (short)hi;
                tlb0[i] = (short)f2bf(tv[i] - bf2f(hi));
            }
            #pragma unroll
            for (int i = 0; i < 8; i++) {
                unsigned short hi = f2bf(tv[8 + i]);
                thb1[i] = (short)hi;
                tlb1[i] = (short)f2bf(tv[8 + i] - bf2f(hi));
            }
        }
        // GEMM2 for both ratings per col-tile + epilogues.
        #pragma unroll
        for (int ct = 0; ct < 4; ct++) {
            float b2a = b2[rr * 64 + (ct << 4) + (l & 15)];
            f32x4 acca = {b2a, b2a, b2a, b2a};
            f32x4 accb = {0.f, 0.f, 0.f, 0.f};
            if (has2) {
                float b2b = b2[rr2 * 64 + (ct << 4) + (l & 15)];
                accb = (f32x4){b2b, b2b, b2b, b2b};
            }
            #pragma unroll
            for (int kc = 0; kc < 2; kc++) {
                const short* fba = wp2a + ((ct * 2 + kc) * 2) * 512 + l * 8;
                const short* fbb = wp2b + ((ct * 2 + kc) * 2) * 512 + l * 8;
                bf16x8 bha = *(const bf16x8*)(fba);
                bf16x8 bla = *(const bf16x8*)(fba + 512);
                bf16x8 bhb = *(const bf16x8*)(fbb);
                bf16x8 blb = *(const bf16x8*)(fbb + 512);
                bf16x8 aha = (kc == 0) ? tha0 : tha1;
                bf16x8 ala = (kc == 0) ? tla0 : tla1;
                bf16x8 ahb = (kc == 0) ? thb0 : thb1;
                bf16x8 alb = (kc == 0) ? tlb0 : tlb1;
                acca = __builtin_amdgcn_mfma_f32_16x16x32_bf16(aha, bha, acca, 0, 0, 0);
                accb = __builtin_amdgcn_mfma_f32_16x16x32_bf16(ahb, bhb, accb, 0, 0, 0);
                acca = __builtin_amdgcn_mfma_f32_16x16x32_bf16(ala, bha, acca, 0, 0, 0);
                accb = __builtin_amdgcn_mfma_f32_16x16x32_bf16(alb, bhb, accb, 0, 0, 0);
                acca = __builtin_amdgcn_mfma_f32_16x16x32_bf16(aha, bla, acca, 0, 0, 0);
                accb = __builtin_amdgcn_mfma_f32_16x16x32_bf16(ahb, blb, accb, 0, 0, 0);
            }
            unsigned short* ppa = prev + (size_t)rr * prevStride + (ct << 4) + (l & 15);
            unsigned short* ppb = prev + (size_t)(has2 ? rr2 : rr) * prevStride
                                + (ct << 4) + (l & 15);
            #pragma unroll
            for (int i = 0; i < 4; i++) {
                bool va = (i == 0) ? va0 : (i == 1) ? va1 : (i == 2) ? va2 : va3;
                bool fl = (i == 0) ? fl0 : (i == 1) ? fl1 : (i == 2) ? fl2 : fl3;
                if (va) {
                    float hva = acca[i];
                    ppa[(size_t)(dr0 + i) * 64] = f2bf(hva);
                    float hvb = 0.f;
                    if (has2) {
                        hvb = accb[i];
                        ppb[(size_t)(dr0 + i) * 64] = f2bf(hvb);
                    }
                    if (fl) oa[ct * 4 + i] += hva + hvb;
                }
            }
        }
    }

    #pragma unroll
    for (int ct = 0; ct < 4; ct++) {
        #pragma unroll
        for (int i = 0; i < 4; i++) {
            bool fl = (i == 0) ? fl0 : (i == 1) ? fl1 : (i == 2) ? fl2 : fl3;
            if (fl) {
                float* o = out_acc + (size_t)(dr0 + i) * 64 + (ct << 4) + (l & 15);
                if (init) *o = oa[ct * 4 + i];
                else *o += oa[ct * 4 + i];
            }
        }
    }
}

// ---------------------------------------------------------------------------
// Gather-SpMM (layers 0/1). Stride-parameterized for RATING-BATCHED launch
// (grid.y=R); doOut=0 in batched mode. Wave owns TWO rows (R21 ILP form).
// ---------------------------------------------------------------------------
__global__ __launch_bounds__(256) void spmm_kernel(
    const unsigned short* __restrict__ prev, unsigned short* __restrict__ next,
    float* __restrict__ out_acc, const int* __restrict__ rp,
    const uint2* __restrict__ rec, const unsigned char* __restrict__ flag, int n,
    long long pvS, long long nxS, long long rpS, long long rcS, int doOut) {
    int rr = blockIdx.y;
    prev += (size_t)rr * pvS;
    next += (size_t)rr * nxS;
    rp += (size_t)rr * rpS;
    rec += (size_t)rr * rcS;
    int wave = (int)((blockIdx.x * (unsigned)blockDim.x + threadIdx.x) >> 6);
    int lane = threadIdx.x & 63;
    int rA = wave * 2;
    if (rA >= n) return;
    int rB = rA + 1;
    int sub = lane >> 4;      // edge group 0..3
    int dl = lane & 15;       // dims [dl*4, dl*4+4)
    int sA = rp[rA], eA = rp[rA + 1];
    int sB = 0, eB = 0;
    if (rB < n) { sB = rp[rB]; eB = rp[rB + 1]; }
    float axA = 0.f, ayA = 0.f, azA = 0.f, awA = 0.f;
    float axB = 0.f, ayB = 0.f, azB = 0.f, awB = 0.f;
    int ewA = sA + sub, ewB = sB + sub;
    while (ewA < eA || ewB < eB) {
        int a1 = ewA + 4, a2 = ewA + 8, a3 = ewA + 12;
        int b1 = ewB + 4, b2 = ewB + 8, b3 = ewB + 12;
        uint2 ra0 = rec[ewA < eA ? ewA : 0];
        uint2 ra1 = rec[a1 < eA ? a1 : 0];
        uint2 ra2 = rec[a2 < eA ? a2 : 0];
        uint2 ra3 = rec[a3 < eA ? a3 : 0];
        uint2 rb0 = rec[ewB < eB ? ewB : 0];
        uint2 rb1 = rec[b1 < eB ? b1 : 0];
        uint2 rb2 = rec[b2 < eB ? b2 : 0];
        uint2 rb3 = rec[b3 < eB ? b3 : 0];
        float vA0 = (ewA < eA) ? __uint_as_float(ra0.y) : 0.f;
        float vA1 = (a1 < eA) ? __uint_as_float(ra1.y) : 0.f;
        float vA2 = (a2 < eA) ? __uint_as_float(ra2.y) : 0.f;
        float vA3 = (a3 < eA) ? __uint_as_float(ra3.y) : 0.f;
        float vB0 = (ewB < eB) ? __uint_as_float(rb0.y) : 0.f;
        float vB1 = (b1 < eB) ? __uint_as_float(rb1.y) : 0.f;
        float vB2 = (b2 < eB) ? __uint_as_float(rb2.y) : 0.f;
        float vB3 = (b3 < eB) ? __uint_as_float(rb3.y) : 0.f;
        ushort4 qa0 = *(const ushort4*)(prev + (size_t)(ra0.x & COLMASK) * 64 + dl * 4);
        ushort4 qa1 = *(const ushort4*)(prev + (size_t)(ra1.x & COLMASK) * 64 + dl * 4);
        ushort4 qa2 = *(const ushort4*)(prev + (size_t)(ra2.x & COLMASK) * 64 + dl * 4);
        ushort4 qa3 = *(const ushort4*)(prev + (size_t)(ra3.x & COLMASK) * 64 + dl * 4);
        ushort4 qb0 = *(const ushort4*)(prev + (size_t)(rb0.x & COLMASK) * 64 + dl * 4);
        ushort4 qb1 = *(const ushort4*)(prev + (size_t)(rb1.x & COLMASK) * 64 + dl * 4);
        ushort4 qb2 = *(const ushort4*)(prev + (size_t)(rb2.x & COLMASK) * 64 + dl * 4);
        ushort4 qb3 = *(const ushort4*)(prev + (size_t)(rb3.x & COLMASK) * 64 + dl * 4);
        axA += vA0 * bf2f(qa0.x) + vA1 * bf2f(qa1.x) + vA2 * bf2f(qa2.x) + vA3 * bf2f(qa3.x);
        ayA += vA0 * bf2f(qa0.y) + vA1 * bf2f(qa1.y) + vA2 * bf2f(qa2.y) + vA3 * bf2f(qa3.y);
        azA += vA0 * bf2f(qa0.z) + vA1 * bf2f(qa1.z) + vA2 * bf2f(qa2.z) + vA3 * bf2f(qa3.z);
        awA += vA0 * bf2f(qa0.w) + vA1 * bf2f(qa1.w) + vA2 * bf2f(qa2.w) + vA3 * bf2f(qa3.w);
        axB += vB0 * bf2f(qb0.x) + vB1 * bf2f(qb1.x) + vB2 * bf2f(qb2.x) + vB3 * bf2f(qb3.x);
        ayB += vB0 * bf2f(qb0.y) + vB1 * bf2f(qb1.y) + vB2 * bf2f(qb2.y) + vB3 * bf2f(qb3.y);
        azB += vB0 * bf2f(qb0.z) + vB1 * bf2f(qb1.z) + vB2 * bf2f(qb2.z) + vB3 * bf2f(qb3.z);
        awB += vB0 * bf2f(qb0.w) + vB1 * bf2f(qb1.w) + vB2 * bf2f(qb2.w) + vB3 * bf2f(qb3.w);
        ewA += 16; ewB += 16;
    }
    axA += __shfl_xor(axA, 16); ayA += __shfl_xor(ayA, 16);
    azA += __shfl_xor(azA, 16); awA += __shfl_xor(awA, 16);
    axA += __shfl_xor(axA, 32); ayA += __shfl_xor(ayA, 32);
    azA += __shfl_xor(azA, 32); awA += __shfl_xor(awA, 32);
    axB += __shfl_xor(axB, 16); ayB += __shfl_xor(ayB, 16);
    azB += __shfl_xor(azB, 16); awB += __shfl_xor(awB, 16);
    axB += __shfl_xor(axB, 32); ayB += __shfl_xor(ayB, 32);
    azB += __shfl_xor(azB, 32); awB += __shfl_xor(awB, 32);
    if (sub == 0) {
        ushort4 nv;
        nv.x = f2bf(axA); nv.y = f2bf(ayA); nv.z = f2bf(azA); nv.w = f2bf(awA);
        *(ushort4*)(next + (size_t)rA * 64 + dl * 4) = nv;
    } else if (sub == 1 && doOut && flag[rA]) {
        float* o = out_acc + (size_t)rA * 64 + dl * 4;
        float4 ov = *(const float4*)o;
        ov.x += axA; ov.y += ayA; ov.z += azA; ov.w += awA;
        *(float4*)o = ov;
    } else if (sub == 2 && rB < n) {
        ushort4 nv;
        nv.x = f2bf(axB); nv.y = f2bf(ayB); nv.z = f2bf(azB); nv.w = f2bf(awB);
        *(ushort4*)(next + (size_t)rB * 64 + dl * 4) = nv;
    } else if (sub == 3 && doOut && rB < n && flag[rB]) {
        float* o = out_acc + (size_t)rB * 64 + dl * 4;
        float4 ov = *(const float4*)o;
        ov.x += axB; ov.y += ayB; ov.z += azB; ov.w += awB;
        *(float4*)o = ov;
    }
}

// ---------------------------------------------------------------------------
// Layer-2 (masked) SpMM: rows from flist, two per wave. Batched (doOut=0):
// combined result bf16 to mout[r][w]; fallback (doOut=1): RMW out_acc.
// ---------------------------------------------------------------------------
__global__ __launch_bounds__(256) void spmm_masked_kernel(
    const unsigned short* __restrict__ prev, float* __restrict__ out_acc,
    const int* __restrict__ rp, const uint2* __restrict__ rec,
    unsigned long long maskbits, const int* __restrict__ flist,
    const int* __restrict__ fcount,
    unsigned short* __restrict__ mout, long long moS,
    long long pvS, long long rpS, long long rcS, int doOut) {
    int rr = blockIdx.y;
    prev += (size_t)rr * pvS;
    rp += (size_t)rr * rpS;
    rec += (size_t)rr * rcS;
    unsigned short* mo = mout + (size_t)rr * moS;
    int wave = (int)((blockIdx.x * (unsigned)blockDim.x + threadIdx.x) >> 6);
    int lane = threadIdx.x & 63;
    int fc = *fcount;
    int w2 = wave * 2;
    if (w2 >= fc) return;
    int rowA = flist[w2];
    int rowB = (w2 + 1 < fc) ? flist[w2 + 1] : -1;
    int sub = lane >> 4;
    int dl = lane & 15;
    int sA = rp[rowA], eA = rp[rowA + 1];
    int sB = 0, eB = 0;
    if (rowB >= 0) { sB = rp[rowB]; eB = rp[rowB + 1]; }
    float axA = 0.f, ayA = 0.f, azA = 0.f, awA = 0.f;
    float axB = 0.f, ayB = 0.f, azB = 0.f, awB = 0.f;
    int ewA = sA + sub, ewB = sB + sub;
    while (ewA < eA || ewB < eB) {
        int a1 = ewA + 4, a2 = ewA + 8, a3 = ewA + 12;
        int b1 = ewB + 4, b2 = ewB + 8, b3 = ewB + 12;
        uint2 ra0 = rec[ewA < eA ? ewA : 0];
        uint2 ra1 = rec[a1 < eA ? a1 : 0];
        uint2 ra2 = rec[a2 < eA ? a2 : 0];
        uint2 ra3 = rec[a3 < eA ? a3 : 0];
        uint2 rb0 = rec[ewB < eB ? ewB : 0];
        uint2 rb1 = rec[b1 < eB ? b1 : 0];
        uint2 rb2 = rec[b2 < eB ? b2 : 0];
        uint2 rb3 = rec[b3 < eB ? b3 : 0];
        float vA0 = (ewA < eA) ? __uint_as_float(ra0.y) : 0.f;
        float vA1 = (a1 < eA) ? __uint_as_float(ra1.y) : 0.f;
        float vA2 = (a2 < eA) ? __uint_as_float(ra2.y) : 0.f;
        float vA3 = (a3 < eA) ? __uint_as_float(ra3.y) : 0.f;
        float vB0 = (ewB < eB) ? __uint_as_float(rb0.y) : 0.f;
        float vB1 = (b1 < eB) ? __uint_as_float(rb1.y) : 0.f;
        float vB2 = (b2 < eB) ? __uint_as_float(rb2.y) : 0.f;
        float vB3 = (b3 < eB) ? __uint_as_float(rb3.y) : 0.f;
        ushort4 qa0 = *(const ushort4*)(prev + (size_t)(ra0.x & COLMASK) * 64 + dl * 4);
        ushort4 qa1 = *(const ushort4*)(prev + (size_t)(ra1.x & COLMASK) * 64 + dl * 4);
        ushort4 qa2 = *(const ushort4*)(prev + (size_t)(ra2.x & COLMASK) * 64 + dl * 4);
        ushort4 qa3 = *(const ushort4*)(prev + (size_t)(ra3.x & COLMASK) * 64 + dl * 4);
        ushort4 qb0 = *(const ushort4*)(prev + (size_t)(rb0.x & COLMASK) * 64 + dl * 4);
        ushort4 qb1 = *(const ushort4*)(prev + (size_t)(rb1.x & COLMASK) * 64 + dl * 4);
        ushort4 qb2 = *(const ushort4*)(prev + (size_t)(rb2.x & COLMASK) * 64 + dl * 4);
        ushort4 qb3 = *(const ushort4*)(prev + (size_t)(rb3.x & COLMASK) * 64 + dl * 4);
        axA += vA0 * bf2f(qa0.x) + vA1 * bf2f(qa1.x) + vA2 * bf2f(qa2.x) + vA3 * bf2f(qa3.x);
        ayA += vA0 * bf2f(qa0.y) + vA1 * bf2f(qa1.y) + vA2 * bf2f(qa2.y) + vA3 * bf2f(qa3.y);
        azA += vA0 * bf2f(qa0.z) + vA1 * bf2f(qa1.z) + vA2 * bf2f(qa2.z) + vA3 * bf2f(qa3.z);
        awA += vA0 * bf2f(qa0.w) + vA1 * bf2f(qa1.w) + vA2 * bf2f(qa2.w) + vA3 * bf2f(qa3.w);
        axB += vB0 * bf2f(qb0.x) + vB1 * bf2f(qb1.x) + vB2 * bf2f(qb2.x) + vB3 * bf2f(qb3.x);
        ayB += vB0 * bf2f(qb0.y) + vB1 * bf2f(qb1.y) + vB2 * bf2f(qb2.y) + vB3 * bf2f(qb3.y);
        azB += vB0 * bf2f(qb0.z) + vB1 * bf2f(qb1.z) + vB2 * bf2f(qb2.z) + vB3 * bf2f(qb3.z);
        awB += vB0 * bf2f(qb0.w) + vB1 * bf2f(qb1.w) + vB2 * bf2f(qb2.w) + vB3 * bf2f(qb3.w);
        ewA += 16; ewB += 16;
    }
    axA += __shfl_xor(axA, 16); ayA += __shfl_xor(ayA, 16);
    azA += __shfl_xor(azA, 16); awA += __shfl_xor(awA, 16);
    axA += __shfl_xor(axA, 32); ayA += __shfl_xor(ayA, 32);
    azA += __shfl_xor(azA, 32); awA += __shfl_xor(awA, 32);
    axB += __shfl_xor(axB, 16); ayB += __shfl_xor(ayB, 16);
    azB += __shfl_xor(azB, 16); awB += __shfl_xor(awB, 16);
    axB += __shfl_xor(axB, 32); ayB += __shfl_xor(ayB, 32);
    azB += __shfl_xor(azB, 32); awB += __shfl_xor(awB, 32);
    if (sub == 0) {
        ushort4 pq = *(const ushort4*)(prev + (size_t)rowA * 64 + dl * 4);
        float px = bf2f(pq.x), py = bf2f(pq.y), pz = bf2f(pq.z), pw = bf2f(pq.w);
        float rx = ((maskbits >> (dl * 4 + 0)) & 1ull) ? axA : px;
        float ry = ((maskbits >> (dl * 4 + 1)) & 1ull) ? ayA : py;
        float rz = ((maskbits >> (dl * 4 + 2)) & 1ull) ? azA : pz;
        float rw = ((maskbits >> (dl * 4 + 3)) & 1ull) ? awA : pw;
        if (doOut) {
            float* o = out_acc + (size_t)rowA * 64 + dl * 4;
            float4 ov = *(const float4*)o;
            ov.x += rx; ov.y += ry; ov.z += rz; ov.w += rw;
            *(float4*)o = ov;
        } else {
            ushort4 mv;
            mv.x = f2bf(rx); mv.y = f2bf(ry); mv.z = f2bf(rz); mv.w = f2bf(rw);
            *(ushort4*)(mo + (size_t)w2 * 64 + dl * 4) = mv;
        }
    } else if (sub == 2 && rowB >= 0) {
        ushort4 pq = *(const ushort4*)(prev + (size_t)rowB * 64 + dl * 4);
        float px = bf2f(pq.x), py = bf2f(pq.y), pz = bf2f(pq.z), pw = bf2f(pq.w);
        float rx = ((maskbits >> (dl * 4 + 0)) & 1ull) ? axB : px;
        float ry = ((maskbits >> (dl * 4 + 1)) & 1ull) ? ayB : py;
        float rz = ((maskbits >> (dl * 4 + 2)) & 1ull) ? azB : pz;
        float rw = ((maskbits >> (dl * 4 + 3)) & 1ull) ? awB : pw;
        if (doOut) {
            float* o = out_acc + (size_t)rowB * 64 + dl * 4;
            float4 ov = *(const float4*)o;
            ov.x += rx; ov.y += ry; ov.z += rz; ov.w += rw;
            *(float4*)o = ov;
        } else {
            ushort4 mv;
            mv.x = f2bf(rx); mv.y = f2bf(ry); mv.z = f2bf(rz); mv.w = f2bf(rw);
            *(ushort4*)(mo + (size_t)(w2 + 1) * 64 + dl * 4) = mv;
        }
    }
}

// ---------------------------------------------------------------------------
// Deferred out_acc sum (batched tier): out_acc += sum_r (bufB_r + bufA_r +
// mout_r) for flagged rows. Race-free.
// ---------------------------------------------------------------------------
__global__ __launch_bounds__(256) void final_sum_kernel(
    float* __restrict__ out_acc, const unsigned short* __restrict__ bufA,
    const unsigned short* __restrict__ bufB, const unsigned short* __restrict__ mout,
    const int* __restrict__ flist, const int* __restrict__ fcount,
    long long sliceS, long long moS, int R) {
    int w = (int)((blockIdx.x * (unsigned)blockDim.x + threadIdx.x) >> 6);
    int lane = threadIdx.x & 63;
    if (w >= *fcount) return;
    int row = flist[w];
    float v = out_acc[(size_t)row * 64 + lane];
    for (int r = 0; r < R; r++) {
        v += bf2f(bufB[(size_t)r * sliceS + (size_t)row * 64 + lane]);
        v += bf2f(bufA[(size_t)r * sliceS + (size_t)row * 64 + lane]);
        v += bf2f(mout[(size_t)r * moS + (size_t)w * 64 + lane]);
    }
    out_acc[(size_t)row * 64 + lane] = v;
}

// ---------------------------------------------------------------------------
__global__ __launch_bounds__(256) void dot_kernel(
    const float* __restrict__ out_acc, const int* __restrict__ users,
    const int* __restrict__ items, float* __restrict__ out,
    int Bn, int U, float scale) {
    int w = (int)((blockIdx.x * (unsigned)blockDim.x + threadIdx.x) >> 6);
    int lane = threadIdx.x & 63;
    if (w >= Bn) return;
    int u = users[w], it = items[w];
    float a = out_acc[(size_t)u * 64 + lane];
    float c = out_acc[((size_t)(U + it)) * 64 + lane];
    float p = a * c;
    #pragma unroll
    for (int off = 32; off > 0; off >>= 1) p += __shfl_down(p, off);
    if (lane == 0) out[w] = p * scale;
}

// ---------------------------------------------------------------------------
extern "C" void kernel_launch(void* const* d_in, const int* in_sizes, int n_in,
                              void* d_out, int out_size, void* d_ws, size_t ws_size,
                              hipStream_t stream) {
    const int* users = (const int*)d_in[0];
    const int* items = (const int*)d_in[1];
    const float* user_emb = (const float*)d_in[2];
    const float* item_emb = (const float*)d_in[3];
    const float* rating_emb = (const float*)d_in[4];
    const float* W1 = (const float*)d_in[5];
    const float* b1 = (const float*)d_in[6];
    const float* W2 = (const float*)d_in[7];
    const float* b2 = (const float*)d_in[8];
    const int* rows = (const int*)d_in[9];
    const int* cols = (const int*)d_in[10];
    const float* vals = (const float*)d_in[11];
    float* out = (float*)d_out;

    const int Dd = 64;
    int U = in_sizes[2] / Dd;
    int I = in_sizes[3] / Dd;
    int R = in_sizes[4] / Dd;
    int N = U + I;
    int E = in_sizes[9] / R;
    int Bn = in_sizes[0];
    int K = (N + NRB - 1) / NRB;    // 256-row buckets
    int nb = (E + EPB - 1) / EPB;
    int maxF = 2 * Bn;

    auto al = [](size_t b) { return (b + 255) & ~(size_t)255; };
    size_t sliceA = al((size_t)N * 64 * 2);
    size_t bufA_all = al((size_t)R * N * 64 * 2);
    size_t bufB_all = al((size_t)R * N * 64 * 2);
    size_t mout_sz = al((size_t)R * maxF * 64 * 2);
    size_t wpack_sz = al((size_t)R * 2 * 4 * 2 * 2 * 64 * 8 * 2);
    size_t common = al((size_t)N * 64 * 4)
        + al((size_t)R * K * 4)
        + al((size_t)R * (K + 1) * 4) + al((size_t)R * nb * K * 4)
        + al((size_t)R * (N + 1) * 4) + al((size_t)R * 64 * 4) + wpack_sz
        + al((size_t)N) + al((size_t)2 * Bn * 4) + al(4);
    size_t rec_one = al((size_t)E * 8);
    size_t rec_all = al((size_t)E * 8 * R);
    int tier = 0;
    if (ws_size >= common + bufA_all + bufB_all + mout_sz + 2 * rec_all + 65536)
        tier = 2;
    else if (ws_size >= common + bufA_all + sliceA + 2 * rec_all + 65536)
        tier = 1;
    int mlpb = (tier >= 1), batched = (tier >= 1);
    size_t bufAsz = mlpb ? bufA_all : sliceA;
    size_t bufBsz = (tier == 2) ? bufB_all : sliceA;
    size_t recsz = batched ? rec_all : rec_one;

    char* p = (char*)d_ws;
    auto carve = [&](size_t bytes) -> char* {
        char* q = p;
        p += (bytes + 255) & ~(size_t)255;
        return q;
    };
    float* out_acc = (float*)carve((size_t)N * 64 * 4);
    unsigned short* bufA = (unsigned short*)carve(bufAsz);
    unsigned short* bufB = (unsigned short*)carve(bufBsz);
    unsigned short* mout = (unsigned short*)carve((tier == 2) ? mout_sz : 0);
    uint2* rec = (uint2*)carve(recsz);
    uint2* srec = (uint2*)carve(recsz);
    int* gcnt = (int*)carve((size_t)R * K * 4);
    int* bptr = (int*)carve((size_t)R * (K + 1) * 4);
    int* blockBase = (int*)carve((size_t)R * nb * K * 4);
    int* row_ptr = (int*)carve((size_t)R * (N + 1) * 4);
    float* c1_all = (float*)carve((size_t)R * 64 * 4);
    short* wpack = (short*)carve(wpack_sz);
    unsigned char* flag = (unsigned char*)carve((size_t)N);
    int* flist = (int*)carve((size_t)2 * Bn * 4);
    int* fcount = (int*)carve(4);

    uint64_t maskbits = compute_mask_bits();

    hipMemsetAsync(flag, 0, (size_t)N, stream);
    hipMemsetAsync(fcount, 0, 4, stream);
    hipMemsetAsync(gcnt, 0, (size_t)R * K * 4, stream);

    flag_kernel<<<(2 * Bn + 255) / 256, 256, 0, stream>>>(users, items, flag, Bn, U);
    flist_kernel<<<(N + 255) / 256, 256, 0, stream>>>(flag, flist, fcount, N);
    c1_kernel<<<R, 64, 0, stream>>>(rating_emb, W1, b1, c1_all);
    packw_kernel<<<R, 256, 0, stream>>>(W1, W2, wpack);

    dim3 cgrid(nb, R);
    bucket_count_kernel<<<cgrid, 1024, 0, stream>>>(rows, gcnt, blockBase, E, K, nb);
    bucket_scan_kernel<<<R, 256, 0, stream>>>(gcnt, bptr, K);

    if (batched) {
        dim3 sgrid(nb, R);
        if (K <= 512)
            bucket_scatter_kernel<<<sgrid, 1024, 0, stream>>>(
                rows, cols, vals, bptr, blockBase, rec, E, K,
                (long long)E, (long long)(K + 1), (long long)nb * K, (long long)E);
        else
            bucket_scatter_legacy<<<sgrid, 1024, 0, stream>>>(
                rows, cols, vals, bptr, blockBase, rec, E, K,
                (long long)E, (long long)(K + 1), (long long)nb * K, (long long)E);
        dim3 ogrid(K, R);
        bucket_sort_kernel<<<ogrid, 256, 0, stream>>>(
            rec, srec, bptr, row_ptr, K, N,
            (long long)E, (long long)(K + 1), (long long)(N + 1));
    }

    if (mlpb)
        mlp_kernel<<<(N + 63) / 64, 256, 0, stream>>>(
            user_emb, item_emb, wpack, c1_all, b2,
            bufA, (long long)N * 64, out_acc, flag, 0, R, N, U, 1);

    int spmm_waves = (N + 1) / 2;
    int spmm_blocks = (spmm_waves + 3) / 4;
    int masked_blocks = (Bn + 3) / 4;

    if (tier == 2) {
        long long slS = (long long)N * 64, rpS = (long long)(N + 1);
        long long rcS = (long long)E, moS = (long long)maxF * 64;
        dim3 g0(spmm_blocks, R), gm(masked_blocks, R);
        spmm_kernel<<<g0, 256, 0, stream>>>(bufA, bufB, out_acc, row_ptr, srec,
                                            flag, N, slS, slS, rpS, rcS, 0);
        spmm_kernel<<<g0, 256, 0, stream>>>(bufB, bufA, out_acc, row_ptr, srec,
                                            flag, N, slS, slS, rpS, rcS, 0);
        spmm_masked_kernel<<<gm, 256, 0, stream>>>(bufA, out_acc, row_ptr, srec,
                                                   maskbits, flist, fcount,
                                                   mout, moS, slS, rpS, rcS, 0);
        final_sum_kernel<<<(maxF * 64 + 255) / 256, 256, 0, stream>>>(
            out_acc, bufA, bufB, mout, flist, fcount, slS, moS, R);
    } else {
        for (int r = 0; r < R; r++) {
            const int* bptr_r = bptr + (size_t)r * (K + 1);
            int* rp_r = row_ptr + (size_t)r * (N + 1);
            uint2* srec_r = batched ? (srec + (size_t)r * E) : srec;
            unsigned short* prev_r = mlpb ? (bufA + (size_t)r * N * 64) : bufA;

            if (!batched) {
                dim3 sgrid(nb, 1);
                if (K <= 512)
                    bucket_scatter_kernel<<<sgrid, 1024, 0, stream>>>(
                        rows + (size_t)r * E, cols + (size_t)r * E, vals + (size_t)r * E,
                        bptr_r, blockBase + (size_t)r * nb * K, rec, E, K, 0, 0, 0, 0);
                else
                    bucket_scatter_legacy<<<sgrid, 1024, 0, stream>>>(
                        rows + (size_t)r * E, cols + (size_t)r * E, vals + (size_t)r * E,
                        bptr_r, blockBase + (size_t)r * nb * K, rec, E, K, 0, 0, 0, 0);
                dim3 ogrid(K, 1);
                bucket_sort_kernel<<<ogrid, 256, 0, stream>>>(
                    rec, srec, bptr_r, rp_r, K, N, 0, 0, 0);
            }

            if (!mlpb)
                mlp_kernel<<<(N + 63) / 64, 256, 0, stream>>>(
                    user_emb, item_emb, wpack, c1_all, b2,
                    bufA, 0, out_acc, flag, r, 1, N, U, (r == 0) ? 1 : 0);

            spmm_kernel<<<spmm_blocks, 256, 0, stream>>>(
                prev_r, bufB, out_acc, rp_r, srec_r, flag, N, 0, 0, 0, 0, 1);
            spmm_kernel<<<spmm_blocks, 256, 0, stream>>>(
                bufB, prev_r, out_acc, rp_r, srec_r, flag, N, 0, 0, 0, 0, 1);
            spmm_masked_kernel<<<masked_blocks, 256, 0, stream>>>(
                prev_r, out_acc, rp_r, srec_r, maskbits, flist, fcount,
                bufB /*unused*/, 0, 0, 0, 0, 1);
        }
    }

    float scale = 1.0f / (float)(R * R);
    dot_kernel<<<(Bn * 64 + 255) / 256, 256, 0, stream>>>(out_acc, users, items, out,
                                                          Bn, U, scale);
}

// Round 14
// 602.839 us; speedup vs baseline: 1.0474x; 1.0474x over previous
//
#include <hip/hip_runtime.h>
#include <hip/hip_bf16.h>
#include <cstdint>
#include <cstddef>

#define KEYSHIFT 20
#define COLMASK 0xFFFFFu
#define EPB 8192    // edges per count/scatter block (1024 threads x 8)
#define SUB 4096    // staged sub-chunk inside scatter (fits 54KB LDS)
#define BSHIFT 8    // 256 rows per bucket
#define NRB 256     // rows per bucket (1 << BSHIFT)
#define CCAP 3072   // LDS sort capacity per bucket (avg ~2560, max ~2750)

typedef short bf16x8 __attribute__((ext_vector_type(8)));
typedef float f32x4 __attribute__((ext_vector_type(4)));

// bf16 pack/unpack: RNE; accumulation fp32.
__device__ __forceinline__ unsigned short f2bf(float f) {
    uint32_t u = __float_as_uint(f);
    u += ((u >> 16) & 1u) + 0x7fffu;   // RNE
    return (unsigned short)(u >> 16);
}
__device__ __forceinline__ float bf2f(unsigned short h) {
    return __uint_as_float(((uint32_t)h) << 16);
}

// ---------------------------------------------------------------------------
// Host-side reproduction of np.random.RandomState(2).permutation(64).
// ---------------------------------------------------------------------------
static uint64_t compute_mask_bits() {
    uint32_t mt[624];
    mt[0] = 2u;
    for (int i = 1; i < 624; i++)
        mt[i] = 1812433253u * (mt[i - 1] ^ (mt[i - 1] >> 30)) + (uint32_t)i;
    int mti = 624;
    auto genrand = [&]() -> uint32_t {
        if (mti >= 624) {
            for (int k = 0; k < 624; k++) {
                uint32_t y = (mt[k] & 0x80000000u) | (mt[(k + 1) % 624] & 0x7fffffffu);
                mt[k] = mt[(k + 397) % 624] ^ (y >> 1) ^ ((y & 1u) ? 2567483615u : 0u);
            }
            mti = 0;
        }
        uint32_t y = mt[mti++];
        y ^= y >> 11;
        y ^= (y << 7) & 2636928640u;
        y ^= (y << 15) & 4022730752u;
        y ^= y >> 18;
        return y;
    };
    int arr[64];
    for (int i = 0; i < 64; i++) arr[i] = i;
    for (int i = 63; i >= 1; i--) {
        uint32_t mask = (uint32_t)i;
        mask |= mask >> 1; mask |= mask >> 2; mask |= mask >> 4;
        mask |= mask >> 8; mask |= mask >> 16;
        uint32_t v;
        do { v = genrand() & mask; } while (v > (uint32_t)i);
        int tmp = arr[i]; arr[i] = arr[v]; arr[v] = tmp;
    }
    uint64_t bits = 0;
    for (int d = 0; d < 64; d++)
        if (arr[d] >= 38) bits |= (1ull << d);
    return bits;
}

// ---------------------------------------------------------------------------
__global__ void flag_kernel(const int* __restrict__ users, const int* __restrict__ items,
                            unsigned char* __restrict__ flag, int B, int U) {
    int i = blockIdx.x * 256 + threadIdx.x;
    if (i < B) flag[users[i]] = 1;
    else if (i < 2 * B) flag[U + items[i - B]] = 1;
}

__global__ void flist_kernel(const unsigned char* __restrict__ flag,
                             int* __restrict__ flist, int* __restrict__ fcount, int n) {
    int i = blockIdx.x * 256 + threadIdx.x;
    if (i < n && flag[i]) {
        int p = atomicAdd(fcount, 1);
        flist[p] = i;
    }
}

// ---------------------------------------------------------------------------
__global__ void c1_kernel(const float* __restrict__ rating_emb, const float* __restrict__ W1,
                          const float* __restrict__ b1, float* __restrict__ c1_all) {
    int r = blockIdx.x;
    int t = threadIdx.x;  // 64 threads
    const float* W1r = W1 + (size_t)r * (128 * 64);
    float acc = b1[r * 64 + t];
    for (int k = 0; k < 64; k++)
        acc += rating_emb[r * 64 + k] * W1r[(64 + k) * 64 + t];
    c1_all[r * 64 + t] = acc;
}

// ---------------------------------------------------------------------------
// Split-bf16 W fragment pack for MFMA mlp (R22, proven).
// ---------------------------------------------------------------------------
__global__ void packw_kernel(const float* __restrict__ W1, const float* __restrict__ W2,
                             short* __restrict__ wpack) {
    int r = blockIdx.x;
    int t = threadIdx.x;  // 256
    const float* W1r = W1 + (size_t)r * (128 * 64);
    const float* W2r = W2 + (size_t)r * (64 * 64);
    for (int e = t; e < 2 * 4 * 2 * 64 * 8; e += 256) {
        int i = e & 7;
        int lane = (e >> 3) & 63;
        int kc = (e >> 9) & 1;
        int ct = (e >> 10) & 3;
        int g = (e >> 12) & 1;
        int k = kc * 32 + ((lane >> 4) << 3) + i;
        int col = (ct << 4) + (lane & 15);
        float w = (g == 0) ? W1r[k * 64 + col] : W2r[k * 64 + col];
        unsigned short hi = f2bf(w);
        unsigned short lo = f2bf(w - bf2f(hi));
        size_t fb = ((((size_t)r * 2 + g) * 4 + ct) * 2 + kc) * 2;
        wpack[(fb + 0) * 512 + lane * 8 + i] = (short)hi;
        wpack[(fb + 1) * 512 + lane * 8 + i] = (short)lo;
    }
}

// ---------------------------------------------------------------------------
// Build pass A (batched): LDS histogram + one reserve-atomic per bucket.
// ---------------------------------------------------------------------------
__global__ __launch_bounds__(1024) void bucket_count_kernel(
    const int* __restrict__ rows, int* __restrict__ gcnt,
    int* __restrict__ blockBase, int E, int K, int nb) {
    __shared__ int hist[2048];
    int r = blockIdx.y, blk = blockIdx.x, t = threadIdx.x;
    for (int i = t; i < K; i += 1024) hist[i] = 0;
    __syncthreads();
    size_t base = (size_t)r * E + (size_t)blk * EPB;
    int cnt = E - blk * EPB;
    if (cnt > EPB) cnt = EPB;
    for (int k = t; k < cnt; k += 1024)
        atomicAdd(&hist[rows[base + k] >> BSHIFT], 1);
    __syncthreads();
    for (int i = t; i < K; i += 1024) {
        int c = hist[i];
        int bb = (c > 0) ? atomicAdd(&gcnt[r * K + i], c) : 0;
        blockBase[((size_t)r * nb + blk) * K + i] = bb;
    }
}

// ---------------------------------------------------------------------------
__global__ void bucket_scan_kernel(const int* __restrict__ gcnt,
                                   int* __restrict__ bptr, int K) {
    __shared__ int sh[256];
    int r = blockIdx.x;
    int t = threadIdx.x;
    int base = t * 8;
    int v[8];
    int s = 0;
    #pragma unroll
    for (int j = 0; j < 8; j++) {
        int idx = base + j;
        v[j] = (idx < K) ? gcnt[r * K + idx] : 0;
        s += v[j];
    }
    sh[t] = s;
    __syncthreads();
    for (int off = 1; off < 256; off <<= 1) {
        int x = (t >= off) ? sh[t - off] : 0;
        __syncthreads();
        sh[t] += x;
        __syncthreads();
    }
    int run = sh[t] - s;
    #pragma unroll
    for (int j = 0; j < 8; j++) {
        int idx = base + j;
        if (idx <= K) bptr[r * (K + 1) + idx] = run;
        run += v[j];
    }
}

// ---------------------------------------------------------------------------
// Build pass B: LDS-STAGED scatter (K <= 512).
// ---------------------------------------------------------------------------
__global__ __launch_bounds__(1024) void bucket_scatter_kernel(
    const int* __restrict__ rows, const int* __restrict__ cols,
    const float* __restrict__ vals, const int* __restrict__ bptr,
    const int* __restrict__ blockBase, uint2* __restrict__ rec,
    int E, int K, long long eStride, long long pStride,
    long long bbStride, long long rStride) {
    __shared__ uint2 staged[SUB];   // 32KB
    __shared__ int gaddr[SUB];      // 16KB
    __shared__ int cursor[512];
    __shared__ int lhist[512];
    __shared__ int aux[512];
    int r = blockIdx.y;
    const int* rows_r = rows + (size_t)r * eStride;
    const int* cols_r = cols + (size_t)r * eStride;
    const float* vals_r = vals + (size_t)r * eStride;
    const int* bptr_r = bptr + (size_t)r * pStride;
    const int* bb_r = blockBase + (size_t)r * bbStride;
    uint2* rec_r = rec + (size_t)r * rStride;
    int blk = blockIdx.x, t = threadIdx.x;
    if (t < 512)
        cursor[t] = (t < K) ? (bptr_r[t] + bb_r[(size_t)blk * K + t]) : 0;
    size_t base = (size_t)blk * EPB;
    int cnt = E - blk * EPB;
    if (cnt > EPB) cnt = EPB;
    for (int c0 = 0; c0 < cnt; c0 += SUB) {
        int scnt = cnt - c0;
        if (scnt > SUB) scnt = SUB;
        if (t < 512) lhist[t] = 0;
        __syncthreads();
        int bkt_[4], lpos_[4];
        uint2 rv_[4];
        #pragma unroll
        for (int q = 0; q < 4; q++) {
            int kk = (q << 10) + t;
            bkt_[q] = -1;
            if (kk < scnt) {
                size_t g = base + c0 + kk;
                int row = rows_r[g];
                int b = row >> BSHIFT;
                bkt_[q] = b;
                rv_[q] = make_uint2(((uint32_t)(row & (NRB - 1)) << KEYSHIFT) |
                                        (uint32_t)cols_r[g],
                                    __float_as_uint(vals_r[g]));
                lpos_[q] = atomicAdd(&lhist[b], 1);
            }
        }
        __syncthreads();
        int v = (t < 512) ? lhist[t] : 0;
        if (t < 512) aux[t] = v;
        __syncthreads();
        for (int off = 1; off < 512; off <<= 1) {
            int x = 0;
            if (t >= off && t < 512) x = aux[t - off];
            __syncthreads();
            if (t < 512) aux[t] += x;
            __syncthreads();
        }
        if (t < 512) {
            int ex = aux[t] - v;
            int gb = cursor[t];
            cursor[t] = gb + v;
            lhist[t] = ex;
            aux[t] = gb - ex;
        }
        __syncthreads();
        #pragma unroll
        for (int q = 0; q < 4; q++) {
            if (bkt_[q] >= 0) {
                int sidx = lhist[bkt_[q]] + lpos_[q];
                staged[sidx] = rv_[q];
                gaddr[sidx] = aux[bkt_[q]] + sidx;
            }
        }
        __syncthreads();
        for (int i = t; i < scnt; i += 1024)
            rec_r[gaddr[i]] = staged[i];
        __syncthreads();
    }
}

// ---------------------------------------------------------------------------
// Build pass B legacy (direct scatter) — only used if K > 512.
// ---------------------------------------------------------------------------
__global__ __launch_bounds__(1024) void bucket_scatter_legacy(
    const int* __restrict__ rows, const int* __restrict__ cols,
    const float* __restrict__ vals, const int* __restrict__ bptr,
    const int* __restrict__ blockBase, uint2* __restrict__ rec,
    int E, int K, long long eStride, long long pStride,
    long long bbStride, long long rStride) {
    __shared__ int cursor[2048];
    int r = blockIdx.y;
    const int* rows_r = rows + (size_t)r * eStride;
    const int* cols_r = cols + (size_t)r * eStride;
    const float* vals_r = vals + (size_t)r * eStride;
    const int* bptr_r = bptr + (size_t)r * pStride;
    const int* bb_r = blockBase + (size_t)r * bbStride;
    uint2* rec_r = rec + (size_t)r * rStride;
    int blk = blockIdx.x, t = threadIdx.x;
    for (int i = t; i < K; i += 1024)
        cursor[i] = bptr_r[i] + bb_r[(size_t)blk * K + i];
    __syncthreads();
    size_t base = (size_t)blk * EPB;
    int cnt = E - blk * EPB;
    if (cnt > EPB) cnt = EPB;
    for (int k = t; k < cnt; k += 1024) {
        int row = rows_r[base + k];
        int b = row >> BSHIFT;
        int pos = atomicAdd(&cursor[b], 1);
        uint32_t key = ((uint32_t)(row & (NRB - 1)) << KEYSHIFT) | (uint32_t)cols_r[base + k];
        rec_r[pos] = make_uint2(key, __float_as_uint(vals_r[base + k]));
    }
}

// ---------------------------------------------------------------------------
// Build pass C: per-bucket counting sort, fully in LDS; emits row_ptr.
// ---------------------------------------------------------------------------
__global__ __launch_bounds__(256) void bucket_sort_kernel(
    const uint2* __restrict__ rec, uint2* __restrict__ srec,
    const int* __restrict__ bptr, int* __restrict__ rp, int K, int N,
    long long rStride, long long pStride, long long rpStride) {
    __shared__ uint2 staged[CCAP];  // 24KB
    __shared__ int hist[NRB];
    __shared__ int excl[NRB];
    int r = blockIdx.y;
    const uint2* rec_r = rec + (size_t)r * rStride;
    uint2* srec_r = srec + (size_t)r * rStride;
    const int* bptr_r = bptr + (size_t)r * pStride;
    int* rp_r = rp + (size_t)r * rpStride;
    int b = blockIdx.x;
    int t = threadIdx.x;          // 256 threads == NRB
    hist[t] = 0;
    __syncthreads();
    int start = bptr_r[b], end = bptr_r[b + 1];
    int m = end - start;
    for (int e = start + t; e < end; e += 256)
        atomicAdd(&hist[rec_r[e].x >> KEYSHIFT], 1);
    __syncthreads();
    int v = hist[t];
    excl[t] = v;
    __syncthreads();
    for (int off = 1; off < 256; off <<= 1) {
        int x = (t >= off) ? excl[t - off] : 0;
        __syncthreads();
        excl[t] += x;
        __syncthreads();
    }
    int ex = excl[t] - v;
    excl[t] = ex;
    hist[t] = 0;
    int row = b * NRB + t;
    if (row < N) rp_r[row] = start + ex;
    if (b == K - 1 && t == 0) rp_r[N] = bptr_r[K];
    __syncthreads();
    if (m <= CCAP) {
        for (int e = start + t; e < end; e += 256) {
            uint2 rr = rec_r[e];
            int rel = (int)(rr.x >> KEYSHIFT);
            int pos = excl[rel] + atomicAdd(&hist[rel], 1);
            staged[pos] = rr;
        }
        __syncthreads();
        for (int i = t; i < m; i += 256)
            srec_r[start + i] = staged[i];
    } else {
        for (int e = start + t; e < end; e += 256) {
            uint2 rr = rec_r[e];
            int rel = (int)(rr.x >> KEYSHIFT);
            int pos = start + excl[rel] + atomicAdd(&hist[rel], 1);
            srec_r[pos] = rr;
        }
    }
}

// ---------------------------------------------------------------------------
// MFMA MLP (R22, proven at 75us): all ratings in one launch, split-bf16.
// R25 NOTE: the R13 paired-rating variant REGRESSED (VGPR/occupancy knee,
// same failure mode as R9) — reverted to this exact R12 form (607us total).
// ---------------------------------------------------------------------------
__global__ __launch_bounds__(256) void mlp_kernel(
    const float* __restrict__ user_emb, const float* __restrict__ item_emb,
    const short* __restrict__ wpack, const float* __restrict__ c1_all,
    const float* __restrict__ b2,
    unsigned short* __restrict__ prev, long long prevStride,
    float* __restrict__ out_acc, const unsigned char* __restrict__ flag,
    int r0, int nr, int n_rows, int U, int init) {
    __shared__ float sT[64 * 68];   // hidden layer, pad-68 (17.4KB)

    int t = threadIdx.x;
    int wv = t >> 6;
    int l = t & 63;
    int row0 = blockIdx.x * 64;
    int arow = row0 + (wv << 4) + (l & 15);      // A-operand row
    int kb = (l >> 4) << 3;                       // k base within 32-chunk
    int trow = (wv << 4) + (l & 15);              // local T row for A-frags

    bf16x8 xh0, xh1, xl0, xl1;
    {
        float xv[16];
        #pragma unroll
        for (int i = 0; i < 16; i++) xv[i] = 0.f;
        if (arow < n_rows) {
            const float* src = (arow < U) ? (user_emb + (size_t)arow * 64)
                                          : (item_emb + (size_t)(arow - U) * 64);
            float4 p0 = *(const float4*)(src + kb);
            float4 p1 = *(const float4*)(src + kb + 4);
            float4 p2 = *(const float4*)(src + 32 + kb);
            float4 p3 = *(const float4*)(src + 32 + kb + 4);
            xv[0] = p0.x; xv[1] = p0.y; xv[2] = p0.z; xv[3] = p0.w;
            xv[4] = p1.x; xv[5] = p1.y; xv[6] = p1.z; xv[7] = p1.w;
            xv[8] = p2.x; xv[9] = p2.y; xv[10] = p2.z; xv[11] = p2.w;
            xv[12] = p3.x; xv[13] = p3.y; xv[14] = p3.z; xv[15] = p3.w;
        }
        #pragma unroll
        for (int i = 0; i < 8; i++) {
            unsigned short hi = f2bf(xv[i]);
            xh0[i] = (short)hi;
            xl0[i] = (short)f2bf(xv[i] - bf2f(hi));
        }
        #pragma unroll
        for (int i = 0; i < 8; i++) {
            unsigned short hi = f2bf(xv[8 + i]);
            xh1[i] = (short)hi;
            xl1[i] = (short)f2bf(xv[8 + i] - bf2f(hi));
        }
    }

    int dr0 = row0 + (wv << 4) + ((l >> 4) << 2);  // D rows dr0..dr0+3
    bool va0 = (dr0 + 0) < n_rows, va1 = (dr0 + 1) < n_rows;
    bool va2 = (dr0 + 2) < n_rows, va3 = (dr0 + 3) < n_rows;
    bool fl0 = va0 && flag[dr0 + 0], fl1 = va1 && flag[dr0 + 1];
    bool fl2 = va2 && flag[dr0 + 2], fl3 = va3 && flag[dr0 + 3];
    float oa[16];
    #pragma unroll
    for (int i = 0; i < 16; i++) oa[i] = 0.f;

    for (int rr = r0; rr < r0 + nr; ++rr) {
        const short* wp1 = wpack + ((size_t)rr * 2 + 0) * 16 * 512;
        const short* wp2 = wpack + ((size_t)rr * 2 + 1) * 16 * 512;

        #pragma unroll
        for (int ct = 0; ct < 4; ct++) {
            float c1v = c1_all[rr * 64 + (ct << 4) + (l & 15)];
            f32x4 acc = {c1v, c1v, c1v, c1v};
            #pragma unroll
            for (int kc = 0; kc < 2; kc++) {
                const short* fb = wp1 + ((ct * 2 + kc) * 2) * 512 + l * 8;
                bf16x8 bh = *(const bf16x8*)(fb);
                bf16x8 bl = *(const bf16x8*)(fb + 512);
                bf16x8 ah = (kc == 0) ? xh0 : xh1;
                bf16x8 al = (kc == 0) ? xl0 : xl1;
                acc = __builtin_amdgcn_mfma_f32_16x16x32_bf16(ah, bh, acc, 0, 0, 0);
                acc = __builtin_amdgcn_mfma_f32_16x16x32_bf16(al, bh, acc, 0, 0, 0);
                acc = __builtin_amdgcn_mfma_f32_16x16x32_bf16(ah, bl, acc, 0, 0, 0);
            }
            #pragma unroll
            for (int i = 0; i < 4; i++) {
                float v = acc[i];
                v = (v >= 0.f) ? v : 0.01f * v;
                sT[((wv << 4) + ((l >> 4) << 2) + i) * 68 + (ct << 4) + (l & 15)] = v;
            }
        }
        bf16x8 th0, th1, tl0, tl1;
        {
            float4 t0 = *(const float4*)(sT + trow * 68 + kb);
            float4 t1 = *(const float4*)(sT + trow * 68 + kb + 4);
            float4 t2 = *(const float4*)(sT + trow * 68 + 32 + kb);
            float4 t3 = *(const float4*)(sT + trow * 68 + 32 + kb + 4);
            float tv[16] = {t0.x, t0.y, t0.z, t0.w, t1.x, t1.y, t1.z, t1.w,
                            t2.x, t2.y, t2.z, t2.w, t3.x, t3.y, t3.z, t3.w};
            #pragma unroll
            for (int i = 0; i < 8; i++) {
                unsigned short hi = f2bf(tv[i]);
                th0[i] = (short)hi;
                tl0[i] = (short)f2bf(tv[i] - bf2f(hi));
            }
            #pragma unroll
            for (int i = 0; i < 8; i++) {
                unsigned short hi = f2bf(tv[8 + i]);
                th1[i] = (short)hi;
                tl1[i] = (short)f2bf(tv[8 + i] - bf2f(hi));
            }
        }
        #pragma unroll
        for (int ct = 0; ct < 4; ct++) {
            float b2v = b2[rr * 64 + (ct << 4) + (l & 15)];
            f32x4 acc = {b2v, b2v, b2v, b2v};
            #pragma unroll
            for (int kc = 0; kc < 2; kc++) {
                const short* fb = wp2 + ((ct * 2 + kc) * 2) * 512 + l * 8;
                bf16x8 bh = *(const bf16x8*)(fb);
                bf16x8 bl = *(const bf16x8*)(fb + 512);
                bf16x8 ah = (kc == 0) ? th0 : th1;
                bf16x8 al = (kc == 0) ? tl0 : tl1;
                acc = __builtin_amdgcn_mfma_f32_16x16x32_bf16(ah, bh, acc, 0, 0, 0);
                acc = __builtin_amdgcn_mfma_f32_16x16x32_bf16(al, bh, acc, 0, 0, 0);
                acc = __builtin_amdgcn_mfma_f32_16x16x32_bf16(ah, bl, acc, 0, 0, 0);
            }
            unsigned short* pp = prev + (size_t)rr * prevStride + (ct << 4) + (l & 15);
            #pragma unroll
            for (int i = 0; i < 4; i++) {
                bool va = (i == 0) ? va0 : (i == 1) ? va1 : (i == 2) ? va2 : va3;
                bool fl = (i == 0) ? fl0 : (i == 1) ? fl1 : (i == 2) ? fl2 : fl3;
                if (va) {
                    float hv = acc[i];
                    pp[(size_t)(dr0 + i) * 64] = f2bf(hv);
                    if (fl) oa[ct * 4 + i] += hv;
                }
            }
        }
    }

    #pragma unroll
    for (int ct = 0; ct < 4; ct++) {
        #pragma unroll
        for (int i = 0; i < 4; i++) {
            bool fl = (i == 0) ? fl0 : (i == 1) ? fl1 : (i == 2) ? fl2 : fl3;
            if (fl) {
                float* o = out_acc + (size_t)(dr0 + i) * 64 + (ct << 4) + (l & 15);
                if (init) *o = oa[ct * 4 + i];
                else *o += oa[ct * 4 + i];
            }
        }
    }
}

// ---------------------------------------------------------------------------
// Gather-SpMM (layers 0/1). Stride-parameterized for RATING-BATCHED launch
// (grid.y=R); doOut=0 in batched mode. Wave owns TWO rows (R21 ILP form).
// ---------------------------------------------------------------------------
__global__ __launch_bounds__(256) void spmm_kernel(
    const unsigned short* __restrict__ prev, unsigned short* __restrict__ next,
    float* __restrict__ out_acc, const int* __restrict__ rp,
    const uint2* __restrict__ rec, const unsigned char* __restrict__ flag, int n,
    long long pvS, long long nxS, long long rpS, long long rcS, int doOut) {
    int rr = blockIdx.y;
    prev += (size_t)rr * pvS;
    next += (size_t)rr * nxS;
    rp += (size_t)rr * rpS;
    rec += (size_t)rr * rcS;
    int wave = (int)((blockIdx.x * (unsigned)blockDim.x + threadIdx.x) >> 6);
    int lane = threadIdx.x & 63;
    int rA = wave * 2;
    if (rA >= n) return;
    int rB = rA + 1;
    int sub = lane >> 4;      // edge group 0..3
    int dl = lane & 15;       // dims [dl*4, dl*4+4)
    int sA = rp[rA], eA = rp[rA + 1];
    int sB = 0, eB = 0;
    if (rB < n) { sB = rp[rB]; eB = rp[rB + 1]; }
    float axA = 0.f, ayA = 0.f, azA = 0.f, awA = 0.f;
    float axB = 0.f, ayB = 0.f, azB = 0.f, awB = 0.f;
    int ewA = sA + sub, ewB = sB + sub;
    while (ewA < eA || ewB < eB) {
        int a1 = ewA + 4, a2 = ewA + 8, a3 = ewA + 12;
        int b1 = ewB + 4, b2 = ewB + 8, b3 = ewB + 12;
        uint2 ra0 = rec[ewA < eA ? ewA : 0];
        uint2 ra1 = rec[a1 < eA ? a1 : 0];
        uint2 ra2 = rec[a2 < eA ? a2 : 0];
        uint2 ra3 = rec[a3 < eA ? a3 : 0];
        uint2 rb0 = rec[ewB < eB ? ewB : 0];
        uint2 rb1 = rec[b1 < eB ? b1 : 0];
        uint2 rb2 = rec[b2 < eB ? b2 : 0];
        uint2 rb3 = rec[b3 < eB ? b3 : 0];
        float vA0 = (ewA < eA) ? __uint_as_float(ra0.y) : 0.f;
        float vA1 = (a1 < eA) ? __uint_as_float(ra1.y) : 0.f;
        float vA2 = (a2 < eA) ? __uint_as_float(ra2.y) : 0.f;
        float vA3 = (a3 < eA) ? __uint_as_float(ra3.y) : 0.f;
        float vB0 = (ewB < eB) ? __uint_as_float(rb0.y) : 0.f;
        float vB1 = (b1 < eB) ? __uint_as_float(rb1.y) : 0.f;
        float vB2 = (b2 < eB) ? __uint_as_float(rb2.y) : 0.f;
        float vB3 = (b3 < eB) ? __uint_as_float(rb3.y) : 0.f;
        ushort4 qa0 = *(const ushort4*)(prev + (size_t)(ra0.x & COLMASK) * 64 + dl * 4);
        ushort4 qa1 = *(const ushort4*)(prev + (size_t)(ra1.x & COLMASK) * 64 + dl * 4);
        ushort4 qa2 = *(const ushort4*)(prev + (size_t)(ra2.x & COLMASK) * 64 + dl * 4);
        ushort4 qa3 = *(const ushort4*)(prev + (size_t)(ra3.x & COLMASK) * 64 + dl * 4);
        ushort4 qb0 = *(const ushort4*)(prev + (size_t)(rb0.x & COLMASK) * 64 + dl * 4);
        ushort4 qb1 = *(const ushort4*)(prev + (size_t)(rb1.x & COLMASK) * 64 + dl * 4);
        ushort4 qb2 = *(const ushort4*)(prev + (size_t)(rb2.x & COLMASK) * 64 + dl * 4);
        ushort4 qb3 = *(const ushort4*)(prev + (size_t)(rb3.x & COLMASK) * 64 + dl * 4);
        axA += vA0 * bf2f(qa0.x) + vA1 * bf2f(qa1.x) + vA2 * bf2f(qa2.x) + vA3 * bf2f(qa3.x);
        ayA += vA0 * bf2f(qa0.y) + vA1 * bf2f(qa1.y) + vA2 * bf2f(qa2.y) + vA3 * bf2f(qa3.y);
        azA += vA0 * bf2f(qa0.z) + vA1 * bf2f(qa1.z) + vA2 * bf2f(qa2.z) + vA3 * bf2f(qa3.z);
        awA += vA0 * bf2f(qa0.w) + vA1 * bf2f(qa1.w) + vA2 * bf2f(qa2.w) + vA3 * bf2f(qa3.w);
        axB += vB0 * bf2f(qb0.x) + vB1 * bf2f(qb1.x) + vB2 * bf2f(qb2.x) + vB3 * bf2f(qb3.x);
        ayB += vB0 * bf2f(qb0.y) + vB1 * bf2f(qb1.y) + vB2 * bf2f(qb2.y) + vB3 * bf2f(qb3.y);
        azB += vB0 * bf2f(qb0.z) + vB1 * bf2f(qb1.z) + vB2 * bf2f(qb2.z) + vB3 * bf2f(qb3.z);
        awB += vB0 * bf2f(qb0.w) + vB1 * bf2f(qb1.w) + vB2 * bf2f(qb2.w) + vB3 * bf2f(qb3.w);
        ewA += 16; ewB += 16;
    }
    axA += __shfl_xor(axA, 16); ayA += __shfl_xor(ayA, 16);
    azA += __shfl_xor(azA, 16); awA += __shfl_xor(awA, 16);
    axA += __shfl_xor(axA, 32); ayA += __shfl_xor(ayA, 32);
    azA += __shfl_xor(azA, 32); awA += __shfl_xor(awA, 32);
    axB += __shfl_xor(axB, 16); ayB += __shfl_xor(ayB, 16);
    azB += __shfl_xor(azB, 16); awB += __shfl_xor(awB, 16);
    axB += __shfl_xor(axB, 32); ayB += __shfl_xor(ayB, 32);
    azB += __shfl_xor(azB, 32); awB += __shfl_xor(awB, 32);
    if (sub == 0) {
        ushort4 nv;
        nv.x = f2bf(axA); nv.y = f2bf(ayA); nv.z = f2bf(azA); nv.w = f2bf(awA);
        *(ushort4*)(next + (size_t)rA * 64 + dl * 4) = nv;
    } else if (sub == 1 && doOut && flag[rA]) {
        float* o = out_acc + (size_t)rA * 64 + dl * 4;
        float4 ov = *(const float4*)o;
        ov.x += axA; ov.y += ayA; ov.z += azA; ov.w += awA;
        *(float4*)o = ov;
    } else if (sub == 2 && rB < n) {
        ushort4 nv;
        nv.x = f2bf(axB); nv.y = f2bf(ayB); nv.z = f2bf(azB); nv.w = f2bf(awB);
        *(ushort4*)(next + (size_t)rB * 64 + dl * 4) = nv;
    } else if (sub == 3 && doOut && rB < n && flag[rB]) {
        float* o = out_acc + (size_t)rB * 64 + dl * 4;
        float4 ov = *(const float4*)o;
        ov.x += axB; ov.y += ayB; ov.z += azB; ov.w += awB;
        *(float4*)o = ov;
    }
}

// ---------------------------------------------------------------------------
// Layer-2 (masked) SpMM: rows from flist, two per wave. Batched (doOut=0):
// combined result bf16 to mout[r][w]; fallback (doOut=1): RMW out_acc.
// ---------------------------------------------------------------------------
__global__ __launch_bounds__(256) void spmm_masked_kernel(
    const unsigned short* __restrict__ prev, float* __restrict__ out_acc,
    const int* __restrict__ rp, const uint2* __restrict__ rec,
    unsigned long long maskbits, const int* __restrict__ flist,
    const int* __restrict__ fcount,
    unsigned short* __restrict__ mout, long long moS,
    long long pvS, long long rpS, long long rcS, int doOut) {
    int rr = blockIdx.y;
    prev += (size_t)rr * pvS;
    rp += (size_t)rr * rpS;
    rec += (size_t)rr * rcS;
    unsigned short* mo = mout + (size_t)rr * moS;
    int wave = (int)((blockIdx.x * (unsigned)blockDim.x + threadIdx.x) >> 6);
    int lane = threadIdx.x & 63;
    int fc = *fcount;
    int w2 = wave * 2;
    if (w2 >= fc) return;
    int rowA = flist[w2];
    int rowB = (w2 + 1 < fc) ? flist[w2 + 1] : -1;
    int sub = lane >> 4;
    int dl = lane & 15;
    int sA = rp[rowA], eA = rp[rowA + 1];
    int sB = 0, eB = 0;
    if (rowB >= 0) { sB = rp[rowB]; eB = rp[rowB + 1]; }
    float axA = 0.f, ayA = 0.f, azA = 0.f, awA = 0.f;
    float axB = 0.f, ayB = 0.f, azB = 0.f, awB = 0.f;
    int ewA = sA + sub, ewB = sB + sub;
    while (ewA < eA || ewB < eB) {
        int a1 = ewA + 4, a2 = ewA + 8, a3 = ewA + 12;
        int b1 = ewB + 4, b2 = ewB + 8, b3 = ewB + 12;
        uint2 ra0 = rec[ewA < eA ? ewA : 0];
        uint2 ra1 = rec[a1 < eA ? a1 : 0];
        uint2 ra2 = rec[a2 < eA ? a2 : 0];
        uint2 ra3 = rec[a3 < eA ? a3 : 0];
        uint2 rb0 = rec[ewB < eB ? ewB : 0];
        uint2 rb1 = rec[b1 < eB ? b1 : 0];
        uint2 rb2 = rec[b2 < eB ? b2 : 0];
        uint2 rb3 = rec[b3 < eB ? b3 : 0];
        float vA0 = (ewA < eA) ? __uint_as_float(ra0.y) : 0.f;
        float vA1 = (a1 < eA) ? __uint_as_float(ra1.y) : 0.f;
        float vA2 = (a2 < eA) ? __uint_as_float(ra2.y) : 0.f;
        float vA3 = (a3 < eA) ? __uint_as_float(ra3.y) : 0.f;
        float vB0 = (ewB < eB) ? __uint_as_float(rb0.y) : 0.f;
        float vB1 = (b1 < eB) ? __uint_as_float(rb1.y) : 0.f;
        float vB2 = (b2 < eB) ? __uint_as_float(rb2.y) : 0.f;
        float vB3 = (b3 < eB) ? __uint_as_float(rb3.y) : 0.f;
        ushort4 qa0 = *(const ushort4*)(prev + (size_t)(ra0.x & COLMASK) * 64 + dl * 4);
        ushort4 qa1 = *(const ushort4*)(prev + (size_t)(ra1.x & COLMASK) * 64 + dl * 4);
        ushort4 qa2 = *(const ushort4*)(prev + (size_t)(ra2.x & COLMASK) * 64 + dl * 4);
        ushort4 qa3 = *(const ushort4*)(prev + (size_t)(ra3.x & COLMASK) * 64 + dl * 4);
        ushort4 qb0 = *(const ushort4*)(prev + (size_t)(rb0.x & COLMASK) * 64 + dl * 4);
        ushort4 qb1 = *(const ushort4*)(prev + (size_t)(rb1.x & COLMASK) * 64 + dl * 4);
        ushort4 qb2 = *(const ushort4*)(prev + (size_t)(rb2.x & COLMASK) * 64 + dl * 4);
        ushort4 qb3 = *(const ushort4*)(prev + (size_t)(rb3.x & COLMASK) * 64 + dl * 4);
        axA += vA0 * bf2f(qa0.x) + vA1 * bf2f(qa1.x) + vA2 * bf2f(qa2.x) + vA3 * bf2f(qa3.x);
        ayA += vA0 * bf2f(qa0.y) + vA1 * bf2f(qa1.y) + vA2 * bf2f(qa2.y) + vA3 * bf2f(qa3.y);
        azA += vA0 * bf2f(qa0.z) + vA1 * bf2f(qa1.z) + vA2 * bf2f(qa2.z) + vA3 * bf2f(qa3.z);
        awA += vA0 * bf2f(qa0.w) + vA1 * bf2f(qa1.w) + vA2 * bf2f(qa2.w) + vA3 * bf2f(qa3.w);
        axB += vB0 * bf2f(qb0.x) + vB1 * bf2f(qb1.x) + vB2 * bf2f(qb2.x) + vB3 * bf2f(qb3.x);
        ayB += vB0 * bf2f(qb0.y) + vB1 * bf2f(qb1.y) + vB2 * bf2f(qb2.y) + vB3 * bf2f(qb3.y);
        azB += vB0 * bf2f(qb0.z) + vB1 * bf2f(qb1.z) + vB2 * bf2f(qb2.z) + vB3 * bf2f(qb3.z);
        awB += vB0 * bf2f(qb0.w) + vB1 * bf2f(qb1.w) + vB2 * bf2f(qb2.w) + vB3 * bf2f(qb3.w);
        ewA += 16; ewB += 16;
    }
    axA += __shfl_xor(axA, 16); ayA += __shfl_xor(ayA, 16);
    azA += __shfl_xor(azA, 16); awA += __shfl_xor(awA, 16);
    axA += __shfl_xor(axA, 32); ayA += __shfl_xor(ayA, 32);
    azA += __shfl_xor(azA, 32); awA += __shfl_xor(awA, 32);
    axB += __shfl_xor(axB, 16); ayB += __shfl_xor(ayB, 16);
    azB += __shfl_xor(azB, 16); awB += __shfl_xor(awB, 16);
    axB += __shfl_xor(axB, 32); ayB += __shfl_xor(ayB, 32);
    azB += __shfl_xor(azB, 32); awB += __shfl_xor(awB, 32);
    if (sub == 0) {
        ushort4 pq = *(const ushort4*)(prev + (size_t)rowA * 64 + dl * 4);
        float px = bf2f(pq.x), py = bf2f(pq.y), pz = bf2f(pq.z), pw = bf2f(pq.w);
        float rx = ((maskbits >> (dl * 4 + 0)) & 1ull) ? axA : px;
        float ry = ((maskbits >> (dl * 4 + 1)) & 1ull) ? ayA : py;
        float rz = ((maskbits >> (dl * 4 + 2)) & 1ull) ? azA : pz;
        float rw = ((maskbits >> (dl * 4 + 3)) & 1ull) ? awA : pw;
        if (doOut) {
            float* o = out_acc + (size_t)rowA * 64 + dl * 4;
            float4 ov = *(const float4*)o;
            ov.x += rx; ov.y += ry; ov.z += rz; ov.w += rw;
            *(float4*)o = ov;
        } else {
            ushort4 mv;
            mv.x = f2bf(rx); mv.y = f2bf(ry); mv.z = f2bf(rz); mv.w = f2bf(rw);
            *(ushort4*)(mo + (size_t)w2 * 64 + dl * 4) = mv;
        }
    } else if (sub == 2 && rowB >= 0) {
        ushort4 pq = *(const ushort4*)(prev + (size_t)rowB * 64 + dl * 4);
        float px = bf2f(pq.x), py = bf2f(pq.y), pz = bf2f(pq.z), pw = bf2f(pq.w);
        float rx = ((maskbits >> (dl * 4 + 0)) & 1ull) ? axB : px;
        float ry = ((maskbits >> (dl * 4 + 1)) & 1ull) ? ayB : py;
        float rz = ((maskbits >> (dl * 4 + 2)) & 1ull) ? azB : pz;
        float rw = ((maskbits >> (dl * 4 + 3)) & 1ull) ? awB : pw;
        if (doOut) {
            float* o = out_acc + (size_t)rowB * 64 + dl * 4;
            float4 ov = *(const float4*)o;
            ov.x += rx; ov.y += ry; ov.z += rz; ov.w += rw;
            *(float4*)o = ov;
        } else {
            ushort4 mv;
            mv.x = f2bf(rx); mv.y = f2bf(ry); mv.z = f2bf(rz); mv.w = f2bf(rw);
            *(ushort4*)(mo + (size_t)(w2 + 1) * 64 + dl * 4) = mv;
        }
    }
}

// ---------------------------------------------------------------------------
// Deferred out_acc sum (batched tier): out_acc += sum_r (bufB_r + bufA_r +
// mout_r) for flagged rows. Race-free.
// ---------------------------------------------------------------------------
__global__ __launch_bounds__(256) void final_sum_kernel(
    float* __restrict__ out_acc, const unsigned short* __restrict__ bufA,
    const unsigned short* __restrict__ bufB, const unsigned short* __restrict__ mout,
    const int* __restrict__ flist, const int* __restrict__ fcount,
    long long sliceS, long long moS, int R) {
    int w = (int)((blockIdx.x * (unsigned)blockDim.x + threadIdx.x) >> 6);
    int lane = threadIdx.x & 63;
    if (w >= *fcount) return;
    int row = flist[w];
    float v = out_acc[(size_t)row * 64 + lane];
    for (int r = 0; r < R; r++) {
        v += bf2f(bufB[(size_t)r * sliceS + (size_t)row * 64 + lane]);
        v += bf2f(bufA[(size_t)r * sliceS + (size_t)row * 64 + lane]);
        v += bf2f(mout[(size_t)r * moS + (size_t)w * 64 + lane]);
    }
    out_acc[(size_t)row * 64 + lane] = v;
}

// ---------------------------------------------------------------------------
__global__ __launch_bounds__(256) void dot_kernel(
    const float* __restrict__ out_acc, const int* __restrict__ users,
    const int* __restrict__ items, float* __restrict__ out,
    int Bn, int U, float scale) {
    int w = (int)((blockIdx.x * (unsigned)blockDim.x + threadIdx.x) >> 6);
    int lane = threadIdx.x & 63;
    if (w >= Bn) return;
    int u = users[w], it = items[w];
    float a = out_acc[(size_t)u * 64 + lane];
    float c = out_acc[((size_t)(U + it)) * 64 + lane];
    float p = a * c;
    #pragma unroll
    for (int off = 32; off > 0; off >>= 1) p += __shfl_down(p, off);
    if (lane == 0) out[w] = p * scale;
}

// ---------------------------------------------------------------------------
extern "C" void kernel_launch(void* const* d_in, const int* in_sizes, int n_in,
                              void* d_out, int out_size, void* d_ws, size_t ws_size,
                              hipStream_t stream) {
    const int* users = (const int*)d_in[0];
    const int* items = (const int*)d_in[1];
    const float* user_emb = (const float*)d_in[2];
    const float* item_emb = (const float*)d_in[3];
    const float* rating_emb = (const float*)d_in[4];
    const float* W1 = (const float*)d_in[5];
    const float* b1 = (const float*)d_in[6];
    const float* W2 = (const float*)d_in[7];
    const float* b2 = (const float*)d_in[8];
    const int* rows = (const int*)d_in[9];
    const int* cols = (const int*)d_in[10];
    const float* vals = (const float*)d_in[11];
    float* out = (float*)d_out;

    const int Dd = 64;
    int U = in_sizes[2] / Dd;
    int I = in_sizes[3] / Dd;
    int R = in_sizes[4] / Dd;
    int N = U + I;
    int E = in_sizes[9] / R;
    int Bn = in_sizes[0];
    int K = (N + NRB - 1) / NRB;    // 256-row buckets
    int nb = (E + EPB - 1) / EPB;
    int maxF = 2 * Bn;

    auto al = [](size_t b) { return (b + 255) & ~(size_t)255; };
    size_t sliceA = al((size_t)N * 64 * 2);
    size_t bufA_all = al((size_t)R * N * 64 * 2);
    size_t bufB_all = al((size_t)R * N * 64 * 2);
    size_t mout_sz = al((size_t)R * maxF * 64 * 2);
    size_t wpack_sz = al((size_t)R * 2 * 4 * 2 * 2 * 64 * 8 * 2);
    size_t common = al((size_t)N * 64 * 4)
        + al((size_t)R * K * 4)
        + al((size_t)R * (K + 1) * 4) + al((size_t)R * nb * K * 4)
        + al((size_t)R * (N + 1) * 4) + al((size_t)R * 64 * 4) + wpack_sz
        + al((size_t)N) + al((size_t)2 * Bn * 4) + al(4);
    size_t rec_one = al((size_t)E * 8);
    size_t rec_all = al((size_t)E * 8 * R);
    int tier = 0;
    if (ws_size >= common + bufA_all + bufB_all + mout_sz + 2 * rec_all + 65536)
        tier = 2;
    else if (ws_size >= common + bufA_all + sliceA + 2 * rec_all + 65536)
        tier = 1;
    int mlpb = (tier >= 1), batched = (tier >= 1);
    size_t bufAsz = mlpb ? bufA_all : sliceA;
    size_t bufBsz = (tier == 2) ? bufB_all : sliceA;
    size_t recsz = batched ? rec_all : rec_one;

    char* p = (char*)d_ws;
    auto carve = [&](size_t bytes) -> char* {
        char* q = p;
        p += (bytes + 255) & ~(size_t)255;
        return q;
    };
    float* out_acc = (float*)carve((size_t)N * 64 * 4);
    unsigned short* bufA = (unsigned short*)carve(bufAsz);
    unsigned short* bufB = (unsigned short*)carve(bufBsz);
    unsigned short* mout = (unsigned short*)carve((tier == 2) ? mout_sz : 0);
    uint2* rec = (uint2*)carve(recsz);
    uint2* srec = (uint2*)carve(recsz);
    int* gcnt = (int*)carve((size_t)R * K * 4);
    int* bptr = (int*)carve((size_t)R * (K + 1) * 4);
    int* blockBase = (int*)carve((size_t)R * nb * K * 4);
    int* row_ptr = (int*)carve((size_t)R * (N + 1) * 4);
    float* c1_all = (float*)carve((size_t)R * 64 * 4);
    short* wpack = (short*)carve(wpack_sz);
    unsigned char* flag = (unsigned char*)carve((size_t)N);
    int* flist = (int*)carve((size_t)2 * Bn * 4);
    int* fcount = (int*)carve(4);

    uint64_t maskbits = compute_mask_bits();

    hipMemsetAsync(flag, 0, (size_t)N, stream);
    hipMemsetAsync(fcount, 0, 4, stream);
    hipMemsetAsync(gcnt, 0, (size_t)R * K * 4, stream);

    flag_kernel<<<(2 * Bn + 255) / 256, 256, 0, stream>>>(users, items, flag, Bn, U);
    flist_kernel<<<(N + 255) / 256, 256, 0, stream>>>(flag, flist, fcount, N);
    c1_kernel<<<R, 64, 0, stream>>>(rating_emb, W1, b1, c1_all);
    packw_kernel<<<R, 256, 0, stream>>>(W1, W2, wpack);

    dim3 cgrid(nb, R);
    bucket_count_kernel<<<cgrid, 1024, 0, stream>>>(rows, gcnt, blockBase, E, K, nb);
    bucket_scan_kernel<<<R, 256, 0, stream>>>(gcnt, bptr, K);

    if (batched) {
        dim3 sgrid(nb, R);
        if (K <= 512)
            bucket_scatter_kernel<<<sgrid, 1024, 0, stream>>>(
                rows, cols, vals, bptr, blockBase, rec, E, K,
                (long long)E, (long long)(K + 1), (long long)nb * K, (long long)E);
        else
            bucket_scatter_legacy<<<sgrid, 1024, 0, stream>>>(
                rows, cols, vals, bptr, blockBase, rec, E, K,
                (long long)E, (long long)(K + 1), (long long)nb * K, (long long)E);
        dim3 ogrid(K, R);
        bucket_sort_kernel<<<ogrid, 256, 0, stream>>>(
            rec, srec, bptr, row_ptr, K, N,
            (long long)E, (long long)(K + 1), (long long)(N + 1));
    }

    if (mlpb)
        mlp_kernel<<<(N + 63) / 64, 256, 0, stream>>>(
            user_emb, item_emb, wpack, c1_all, b2,
            bufA, (long long)N * 64, out_acc, flag, 0, R, N, U, 1);

    int spmm_waves = (N + 1) / 2;
    int spmm_blocks = (spmm_waves + 3) / 4;
    int masked_blocks = (Bn + 3) / 4;

    if (tier == 2) {
        long long slS = (long long)N * 64, rpS = (long long)(N + 1);
        long long rcS = (long long)E, moS = (long long)maxF * 64;
        dim3 g0(spmm_blocks, R), gm(masked_blocks, R);
        spmm_kernel<<<g0, 256, 0, stream>>>(bufA, bufB, out_acc, row_ptr, srec,
                                            flag, N, slS, slS, rpS, rcS, 0);
        spmm_kernel<<<g0, 256, 0, stream>>>(bufB, bufA, out_acc, row_ptr, srec,
                                            flag, N, slS, slS, rpS, rcS, 0);
        spmm_masked_kernel<<<gm, 256, 0, stream>>>(bufA, out_acc, row_ptr, srec,
                                                   maskbits, flist, fcount,
                                                   mout, moS, slS, rpS, rcS, 0);
        final_sum_kernel<<<(maxF * 64 + 255) / 256, 256, 0, stream>>>(
            out_acc, bufA, bufB, mout, flist, fcount, slS, moS, R);
    } else {
        for (int r = 0; r < R; r++) {
            const int* bptr_r = bptr + (size_t)r * (K + 1);
            int* rp_r = row_ptr + (size_t)r * (N + 1);
            uint2* srec_r = batched ? (srec + (size_t)r * E) : srec;
            unsigned short* prev_r = mlpb ? (bufA + (size_t)r * N * 64) : bufA;

            if (!batched) {
                dim3 sgrid(nb, 1);
                if (K <= 512)
                    bucket_scatter_kernel<<<sgrid, 1024, 0, stream>>>(
                        rows + (size_t)r * E, cols + (size_t)r * E, vals + (size_t)r * E,
                        bptr_r, blockBase + (size_t)r * nb * K, rec, E, K, 0, 0, 0, 0);
                else
                    bucket_scatter_legacy<<<sgrid, 1024, 0, stream>>>(
                        rows + (size_t)r * E, cols + (size_t)r * E, vals + (size_t)r * E,
                        bptr_r, blockBase + (size_t)r * nb * K, rec, E, K, 0, 0, 0, 0);
                dim3 ogrid(K, 1);
                bucket_sort_kernel<<<ogrid, 256, 0, stream>>>(
                    rec, srec, bptr_r, rp_r, K, N, 0, 0, 0);
            }

            if (!mlpb)
                mlp_kernel<<<(N + 63) / 64, 256, 0, stream>>>(
                    user_emb, item_emb, wpack, c1_all, b2,
                    bufA, 0, out_acc, flag, r, 1, N, U, (r == 0) ? 1 : 0);

            spmm_kernel<<<spmm_blocks, 256, 0, stream>>>(
                prev_r, bufB, out_acc, rp_r, srec_r, flag, N, 0, 0, 0, 0, 1);
            spmm_kernel<<<spmm_blocks, 256, 0, stream>>>(
                bufB, prev_r, out_acc, rp_r, srec_r, flag, N, 0, 0, 0, 0, 1);
            spmm_masked_kernel<<<masked_blocks, 256, 0, stream>>>(
                prev_r, out_acc, rp_r, srec_r, maskbits, flist, fcount,
                bufB /*unused*/, 0, 0, 0, 0, 1);
        }
    }

    float scale = 1.0f / (float)(R * R);
    dot_kernel<<<(Bn * 64 + 255) / 256, 256, 0, stream>>>(out_acc, users, items, out,
                                                          Bn, U, scale);
}